// Round 2
// baseline (1108.326 us; speedup 1.0000x reference)
//
#include <hip/hip_runtime.h>
#include <math.h>

// ---------- helpers ----------
__device__ __forceinline__ float elu_f(float v) {
    return v > 0.f ? v : expm1f(v);
}

// ---------- K1: deg[dst] += ew ----------
__global__ __launch_bounds__(256) void k_deg(const int* __restrict__ dst,
                                             const float* __restrict__ ew,
                                             float* __restrict__ deg, int E) {
    int i = blockIdx.x * 256 + threadIdx.x;
    if (i < E) unsafeAtomicAdd(&deg[dst[i]], ew[i]);
}

// ---------- K2: dinv = rsqrt(deg + 1) (in place) ----------
__global__ __launch_bounds__(256) void k_dinv(float* __restrict__ deg, int n) {
    int i = blockIdx.x * 256 + threadIdx.x;
    if (i < n) deg[i] = rsqrtf(deg[i] + 1.0f);
}

// ---------- K3: xw1 = emb[ni] @ W1 ; xf = elu(emb[ni] @ Wf + bf) ----------
__global__ __launch_bounds__(256) void k_front(
    const int* __restrict__ node_index,
    const float* __restrict__ emb,
    const float* __restrict__ W1,
    const float* __restrict__ Wf,
    const float* __restrict__ bfv,
    float* __restrict__ xw1,
    float* __restrict__ xf,
    int n)
{
    __shared__ float sW1[4096];
    __shared__ float sWf[4096];
    __shared__ float sbf[64];
    int tid = threadIdx.x;
    for (int i = tid; i < 1024; i += 256) {
        ((float4*)sW1)[i] = ((const float4*)W1)[i];
        ((float4*)sWf)[i] = ((const float4*)Wf)[i];
    }
    if (tid < 16) ((float4*)sbf)[tid] = ((const float4*)bfv)[tid];
    __syncthreads();
    int r = blockIdx.x * 256 + tid;
    if (r >= n) return;
    int idx = node_index[r];
    float x[64];
    const float4* xr = (const float4*)(emb + (long long)idx * 64);
    #pragma unroll
    for (int i = 0; i < 16; ++i) {
        float4 v = xr[i];
        x[4*i+0] = v.x; x[4*i+1] = v.y; x[4*i+2] = v.z; x[4*i+3] = v.w;
    }
    float4* o1 = (float4*)(xw1 + (long long)r * 64);
    float4* of = (float4*)(xf  + (long long)r * 64);
    #pragma unroll 1
    for (int h0 = 0; h0 < 64; h0 += 4) {
        float a0=0,a1=0,a2=0,a3=0, f0=0,f1=0,f2=0,f3=0;
        #pragma unroll
        for (int k = 0; k < 64; ++k) {
            float xk = x[k];
            float4 w1 = *(const float4*)(sW1 + k*64 + h0);  // broadcast, conflict-free
            float4 wf = *(const float4*)(sWf + k*64 + h0);
            a0 = fmaf(xk, w1.x, a0); a1 = fmaf(xk, w1.y, a1);
            a2 = fmaf(xk, w1.z, a2); a3 = fmaf(xk, w1.w, a3);
            f0 = fmaf(xk, wf.x, f0); f1 = fmaf(xk, wf.y, f1);
            f2 = fmaf(xk, wf.z, f2); f3 = fmaf(xk, wf.w, f3);
        }
        float4 b = *(const float4*)(sbf + h0);
        float4 r1; r1.x=a0; r1.y=a1; r1.z=a2; r1.w=a3;
        o1[h0>>2] = r1;
        float4 rf;
        rf.x = elu_f(f0 + b.x); rf.y = elu_f(f1 + b.y);
        rf.z = elu_f(f2 + b.z); rf.w = elu_f(f3 + b.w);
        of[h0>>2] = rf;
    }
}

// ---------- K4/K6: edge scatter — one wave per edge, lane = feature dim ----------
__global__ __launch_bounds__(256) void k_scatter(
    const int* __restrict__ src,
    const int* __restrict__ dst,
    const float* __restrict__ ew,
    const float* __restrict__ dinv,
    const float* __restrict__ xw,
    float* __restrict__ agg,
    int E)
{
    long long gid = (long long)blockIdx.x * 256 + threadIdx.x;
    int e = (int)(gid >> 6);
    int lane = (int)(gid & 63);
    if (e >= E) return;
    int s = src[e], d = dst[e];
    float norm = dinv[s] * ew[e] * dinv[d];
    float v = xw[(long long)s * 64 + lane] * norm;
    unsafeAtomicAdd(agg + (long long)d * 64 + lane, v);
}

// ---------- K5: x1 = elu(agg1 + xw1*dinv2 + b1) ; xw2 = xf @ W2 ----------
__global__ __launch_bounds__(256) void k_mid(
    const float* __restrict__ agg1,
    const float* __restrict__ xw1,
    const float* __restrict__ dinv,
    const float* __restrict__ b1,
    const float* __restrict__ xf,
    const float* __restrict__ W2,
    float* __restrict__ x1,
    float* __restrict__ xw2,
    int n)
{
    __shared__ float sW2[4096];
    __shared__ float sb1[64];
    int tid = threadIdx.x;
    for (int i = tid; i < 1024; i += 256)
        ((float4*)sW2)[i] = ((const float4*)W2)[i];
    if (tid < 16) ((float4*)sb1)[tid] = ((const float4*)b1)[tid];
    __syncthreads();
    int r = blockIdx.x * 256 + tid;
    if (r >= n) return;
    float di = dinv[r];
    float di2 = di * di;
    const float4* pa = (const float4*)(agg1 + (long long)r * 64);
    const float4* pw = (const float4*)(xw1  + (long long)r * 64);
    float4* px1 = (float4*)(x1 + (long long)r * 64);
    #pragma unroll
    for (int i = 0; i < 16; ++i) {
        float4 a = pa[i], w = pw[i];
        float4 b = *(const float4*)(sb1 + 4*i);
        float4 o;
        o.x = elu_f(a.x + w.x*di2 + b.x);
        o.y = elu_f(a.y + w.y*di2 + b.y);
        o.z = elu_f(a.z + w.z*di2 + b.z);
        o.w = elu_f(a.w + w.w*di2 + b.w);
        px1[i] = o;
    }
    // xw2 = xf @ W2
    float x[64];
    const float4* xr = (const float4*)(xf + (long long)r * 64);
    #pragma unroll
    for (int i = 0; i < 16; ++i) {
        float4 v = xr[i];
        x[4*i+0] = v.x; x[4*i+1] = v.y; x[4*i+2] = v.z; x[4*i+3] = v.w;
    }
    float4* o2 = (float4*)(xw2 + (long long)r * 64);
    #pragma unroll 1
    for (int h0 = 0; h0 < 64; h0 += 4) {
        float a0=0,a1=0,a2=0,a3=0;
        #pragma unroll
        for (int k = 0; k < 64; ++k) {
            float xk = x[k];
            float4 w2 = *(const float4*)(sW2 + k*64 + h0);
            a0 = fmaf(xk, w2.x, a0); a1 = fmaf(xk, w2.y, a1);
            a2 = fmaf(xk, w2.z, a2); a3 = fmaf(xk, w2.w, a3);
        }
        float4 r2; r2.x=a0; r2.y=a1; r2.z=a2; r2.w=a3;
        o2[h0>>2] = r2;
    }
}

// ---------- K7: h2 = elu(agg2 + xw2*dinv2 + b2); x = x1 + h2;
//              logits = x @ Wl + bl; out = log_softmax(logits) ----------
__global__ __launch_bounds__(256) void k_back(
    const float* __restrict__ agg2,
    const float* __restrict__ xw2,
    const float* __restrict__ dinv,
    const float* __restrict__ b2,
    const float* __restrict__ x1,
    const float* __restrict__ Wl,
    const float* __restrict__ bl,
    float* __restrict__ out,
    int n)
{
    __shared__ float sWl[1024];  // 64 x 16
    __shared__ float sbl[16];
    __shared__ float sb2[64];
    int tid = threadIdx.x;
    if (tid < 256) ((float4*)sWl)[tid] = ((const float4*)Wl)[tid];
    if (tid < 4)  ((float4*)sbl)[tid] = ((const float4*)bl)[tid];
    if (tid < 16) ((float4*)sb2)[tid] = ((const float4*)b2)[tid];
    __syncthreads();
    int r = blockIdx.x * 256 + tid;
    if (r >= n) return;
    float di = dinv[r];
    float di2 = di * di;
    float x[64];
    const float4* pa = (const float4*)(agg2 + (long long)r * 64);
    const float4* pw = (const float4*)(xw2  + (long long)r * 64);
    const float4* p1 = (const float4*)(x1   + (long long)r * 64);
    #pragma unroll
    for (int i = 0; i < 16; ++i) {
        float4 a = pa[i], w = pw[i], o = p1[i];
        float4 b = *(const float4*)(sb2 + 4*i);
        x[4*i+0] = o.x + elu_f(a.x + w.x*di2 + b.x);
        x[4*i+1] = o.y + elu_f(a.y + w.y*di2 + b.y);
        x[4*i+2] = o.z + elu_f(a.z + w.z*di2 + b.z);
        x[4*i+3] = o.w + elu_f(a.w + w.w*di2 + b.w);
    }
    float lg[16];
    #pragma unroll 1
    for (int c0 = 0; c0 < 16; c0 += 4) {
        float4 bb = *(const float4*)(sbl + c0);
        float l0=bb.x, l1=bb.y, l2=bb.z, l3=bb.w;
        #pragma unroll
        for (int d = 0; d < 64; ++d) {
            float xd = x[d];
            float4 wl = *(const float4*)(sWl + d*16 + c0);
            l0 = fmaf(xd, wl.x, l0); l1 = fmaf(xd, wl.y, l1);
            l2 = fmaf(xd, wl.z, l2); l3 = fmaf(xd, wl.w, l3);
        }
        lg[c0]=l0; lg[c0+1]=l1; lg[c0+2]=l2; lg[c0+3]=l3;
    }
    float m = lg[0];
    #pragma unroll
    for (int c = 1; c < 16; ++c) m = fmaxf(m, lg[c]);
    float ssum = 0.f;
    #pragma unroll
    for (int c = 0; c < 16; ++c) ssum += __expf(lg[c] - m);
    float lse = m + __logf(ssum);
    float4* po = (float4*)(out + (long long)r * 16);
    #pragma unroll
    for (int c0 = 0; c0 < 16; c0 += 4) {
        float4 o;
        o.x = lg[c0+0]-lse; o.y = lg[c0+1]-lse;
        o.z = lg[c0+2]-lse; o.w = lg[c0+3]-lse;
        po[c0>>2] = o;
    }
}

// ---------- launch ----------
extern "C" void kernel_launch(void* const* d_in, const int* in_sizes, int n_in,
                              void* d_out, int out_size, void* d_ws, size_t ws_size,
                              hipStream_t stream)
{
    const int*   node_index = (const int*)d_in[0];
    const int*   edge_index = (const int*)d_in[1];
    const float* ew  = (const float*)d_in[2];
    const float* emb = (const float*)d_in[3];
    const float* W1  = (const float*)d_in[4];
    const float* b1  = (const float*)d_in[5];
    const float* W2  = (const float*)d_in[6];
    const float* b2  = (const float*)d_in[7];
    const float* Wf  = (const float*)d_in[8];
    const float* bfv = (const float*)d_in[9];
    const float* Wl  = (const float*)d_in[10];
    const float* bl  = (const float*)d_in[11];

    const int N = in_sizes[0];
    const int E = in_sizes[2];
    const int* srcp = edge_index;
    const int* dstp = edge_index + E;

    char* ws = (char*)d_ws;
    size_t off = 0;
    auto alloc = [&](size_t bytes) {
        void* p = ws + off;
        off += (bytes + 255) & ~size_t(255);
        return p;
    };
    float* deg = (float*)alloc((size_t)N * 4);        // becomes dinv in-place
    float* xw1 = (float*)alloc((size_t)N * 64 * 4);
    float* xf  = (float*)alloc((size_t)N * 64 * 4);
    float* agg = (float*)alloc((size_t)N * 64 * 4);   // agg1, later reused as agg2
    float* xw2 = (float*)alloc((size_t)N * 64 * 4);
    float* x1  = (float*)alloc((size_t)N * 64 * 4);

    int nb_nodes = (N + 255) / 256;
    int nb_edges = (E + 255) / 256;
    int nb_scat  = (int)(((long long)E * 64 + 255) / 256);

    hipMemsetAsync(deg, 0, (size_t)N * 4, stream);
    hipMemsetAsync(agg, 0, (size_t)N * 64 * 4, stream);
    k_deg<<<nb_edges, 256, 0, stream>>>(dstp, ew, deg, E);
    k_dinv<<<nb_nodes, 256, 0, stream>>>(deg, N);
    k_front<<<nb_nodes, 256, 0, stream>>>(node_index, emb, W1, Wf, bfv, xw1, xf, N);
    k_scatter<<<nb_scat, 256, 0, stream>>>(srcp, dstp, ew, deg, xw1, agg, E);
    k_mid<<<nb_nodes, 256, 0, stream>>>(agg, xw1, deg, b1, xf, W2, x1, xw2, N);
    hipMemsetAsync(agg, 0, (size_t)N * 64 * 4, stream);   // stream-ordered after k_mid
    k_scatter<<<nb_scat, 256, 0, stream>>>(srcp, dstp, ew, deg, xw2, agg, E);
    k_back<<<nb_nodes, 256, 0, stream>>>(agg, xw2, deg, b2, x1, Wl, bl, (float*)d_out, N);
}

// Round 3
// 760.885 us; speedup vs baseline: 1.4566x; 1.4566x over previous
//
#include <hip/hip_runtime.h>
#include <math.h>

// ---------- helpers ----------
__device__ __forceinline__ float elu_f(float v) {
    return v > 0.f ? v : expm1f(v);
}

// ---------- K1: deg[dst] += ew ; cnt[dst] += 1 ----------
__global__ __launch_bounds__(256) void k_deg_cnt(const int* __restrict__ dst,
                                                 const float* __restrict__ ew,
                                                 float* __restrict__ deg,
                                                 int* __restrict__ cnt, int E) {
    int i = blockIdx.x * 256 + threadIdx.x;
    if (i < E) {
        int d = dst[i];
        unsafeAtomicAdd(&deg[d], ew[i]);
        atomicAdd(&cnt[d], 1);
    }
}

// ---------- K2: dinv = rsqrt(deg + 1) (in place) ----------
__global__ __launch_bounds__(256) void k_dinv(float* __restrict__ deg, int n) {
    int i = blockIdx.x * 256 + threadIdx.x;
    if (i < n) deg[i] = rsqrtf(deg[i] + 1.0f);
}

// ---------- scan step 1: per-block sums of cnt ----------
__global__ __launch_bounds__(256) void k_blocksum(const int* __restrict__ cnt,
                                                  int* __restrict__ bsum, int n) {
    __shared__ int sm[256];
    int t = threadIdx.x;
    int i = blockIdx.x * 256 + t;
    sm[t] = (i < n) ? cnt[i] : 0;
    __syncthreads();
    for (int off = 128; off > 0; off >>= 1) {
        if (t < off) sm[t] += sm[t + off];
        __syncthreads();
    }
    if (t == 0) bsum[blockIdx.x] = sm[0];
}

// ---------- scan step 2: exclusive scan of block sums (single block, nb<=512) ----------
__global__ __launch_bounds__(512) void k_scan_bsum(int* __restrict__ bsum, int nb) {
    __shared__ int sm[512];
    int t = threadIdx.x;
    int v = (t < nb) ? bsum[t] : 0;
    sm[t] = v;
    __syncthreads();
    for (int off = 1; off < 512; off <<= 1) {
        int x = sm[t];
        int y = (t >= off) ? sm[t - off] : 0;
        __syncthreads();
        sm[t] = x + y;
        __syncthreads();
    }
    if (t < nb) bsum[t] = sm[t] - v;   // exclusive
}

// ---------- scan step 3: rowptr = blockoff + intra-block exclusive scan ----------
__global__ __launch_bounds__(256) void k_scan_apply(const int* __restrict__ cnt,
                                                    const int* __restrict__ bsum,
                                                    int* __restrict__ rowptr,
                                                    int* __restrict__ cursor, int n) {
    __shared__ int sm[256];
    int t = threadIdx.x;
    int i = blockIdx.x * 256 + t;
    int v = (i < n) ? cnt[i] : 0;
    sm[t] = v;
    __syncthreads();
    for (int off = 1; off < 256; off <<= 1) {
        int x = sm[t];
        int y = (t >= off) ? sm[t - off] : 0;
        __syncthreads();
        sm[t] = x + y;
        __syncthreads();
    }
    int excl = sm[t] - v + bsum[blockIdx.x];
    if (i < n) {
        rowptr[i] = excl;
        cursor[i] = excl;
        if (i == n - 1) rowptr[n] = excl + v;
    }
}

// ---------- K-fill: counting-sort edges by dst; meta = (src, norm) ----------
__global__ __launch_bounds__(256) void k_fill(const int* __restrict__ src,
                                              const int* __restrict__ dst,
                                              const float* __restrict__ ew,
                                              const float* __restrict__ dinv,
                                              int* __restrict__ cursor,
                                              int2* __restrict__ meta, int E) {
    int i = blockIdx.x * 256 + threadIdx.x;
    if (i >= E) return;
    int s = src[i], d = dst[i];
    float nrm = dinv[s] * ew[i] * dinv[d];
    int pos = atomicAdd(&cursor[d], 1);
    meta[pos] = make_int2(s, __float_as_int(nrm));
}

// ---------- K-front: xw1 = emb[ni] @ W1 ; xf = elu(emb[ni] @ Wf + bf) ----------
__global__ __launch_bounds__(256) void k_front(
    const int* __restrict__ node_index,
    const float* __restrict__ emb,
    const float* __restrict__ W1,
    const float* __restrict__ Wf,
    const float* __restrict__ bfv,
    float* __restrict__ xw1,
    float* __restrict__ xf,
    int n)
{
    __shared__ float sW1[4096];
    __shared__ float sWf[4096];
    __shared__ float sbf[64];
    int tid = threadIdx.x;
    for (int i = tid; i < 1024; i += 256) {
        ((float4*)sW1)[i] = ((const float4*)W1)[i];
        ((float4*)sWf)[i] = ((const float4*)Wf)[i];
    }
    if (tid < 16) ((float4*)sbf)[tid] = ((const float4*)bfv)[tid];
    __syncthreads();
    int r = blockIdx.x * 256 + tid;
    if (r >= n) return;
    int idx = node_index[r];
    float x[64];
    const float4* xr = (const float4*)(emb + (long long)idx * 64);
    #pragma unroll
    for (int i = 0; i < 16; ++i) {
        float4 v = xr[i];
        x[4*i+0] = v.x; x[4*i+1] = v.y; x[4*i+2] = v.z; x[4*i+3] = v.w;
    }
    float4* o1 = (float4*)(xw1 + (long long)r * 64);
    float4* of = (float4*)(xf  + (long long)r * 64);
    #pragma unroll 1
    for (int h0 = 0; h0 < 64; h0 += 4) {
        float a0=0,a1=0,a2=0,a3=0, f0=0,f1=0,f2=0,f3=0;
        #pragma unroll
        for (int k = 0; k < 64; ++k) {
            float xk = x[k];
            float4 w1 = *(const float4*)(sW1 + k*64 + h0);  // broadcast, conflict-free
            float4 wf = *(const float4*)(sWf + k*64 + h0);
            a0 = fmaf(xk, w1.x, a0); a1 = fmaf(xk, w1.y, a1);
            a2 = fmaf(xk, w1.z, a2); a3 = fmaf(xk, w1.w, a3);
            f0 = fmaf(xk, wf.x, f0); f1 = fmaf(xk, wf.y, f1);
            f2 = fmaf(xk, wf.z, f2); f3 = fmaf(xk, wf.w, f3);
        }
        float4 b = *(const float4*)(sbf + h0);
        float4 r1; r1.x=a0; r1.y=a1; r1.z=a2; r1.w=a3;
        o1[h0>>2] = r1;
        float4 rf;
        rf.x = elu_f(f0 + b.x); rf.y = elu_f(f1 + b.y);
        rf.z = elu_f(f2 + b.z); rf.w = elu_f(f3 + b.w);
        of[h0>>2] = rf;
    }
}

// ---------- K-gather: one wave per dst node, lane = feature dim ----------
// out[d] = elu( sum_e xw[src_e]*norm_e + xw[d]*dinv[d]^2 + bias ) [+ addin[d]]
template<bool ADD>
__global__ __launch_bounds__(256) void k_gather(
    const int2* __restrict__ meta,
    const int*  __restrict__ rowptr,
    const float* __restrict__ dinv,
    const float* __restrict__ xw,
    const float* __restrict__ bias,
    const float* __restrict__ addin,
    float* __restrict__ outp,
    int n)
{
    int wid  = threadIdx.x >> 6;
    int lane = threadIdx.x & 63;
    int d = blockIdx.x * 4 + wid;
    if (d >= n) return;
    float di = dinv[d];
    float acc = xw[(long long)d * 64 + lane] * di * di;   // self-loop term
    int e0 = rowptr[d], e1 = rowptr[d + 1];
    for (int e = e0; e < e1; ++e) {
        int2 m = meta[e];                                  // broadcast 8B load
        acc = fmaf(xw[(long long)m.x * 64 + lane], __int_as_float(m.y), acc);
    }
    float r = elu_f(acc + bias[lane]);
    if (ADD) r += addin[(long long)d * 64 + lane];
    outp[(long long)d * 64 + lane] = r;
}

// ---------- K-mid: xw2 = xf @ W2 ----------
__global__ __launch_bounds__(256) void k_mid(
    const float* __restrict__ xf,
    const float* __restrict__ W2,
    float* __restrict__ xw2,
    int n)
{
    __shared__ float sW2[4096];
    int tid = threadIdx.x;
    for (int i = tid; i < 1024; i += 256)
        ((float4*)sW2)[i] = ((const float4*)W2)[i];
    __syncthreads();
    int r = blockIdx.x * 256 + tid;
    if (r >= n) return;
    float x[64];
    const float4* xr = (const float4*)(xf + (long long)r * 64);
    #pragma unroll
    for (int i = 0; i < 16; ++i) {
        float4 v = xr[i];
        x[4*i+0] = v.x; x[4*i+1] = v.y; x[4*i+2] = v.z; x[4*i+3] = v.w;
    }
    float4* o2 = (float4*)(xw2 + (long long)r * 64);
    #pragma unroll 1
    for (int h0 = 0; h0 < 64; h0 += 4) {
        float a0=0,a1=0,a2=0,a3=0;
        #pragma unroll
        for (int k = 0; k < 64; ++k) {
            float xk = x[k];
            float4 w2 = *(const float4*)(sW2 + k*64 + h0);
            a0 = fmaf(xk, w2.x, a0); a1 = fmaf(xk, w2.y, a1);
            a2 = fmaf(xk, w2.z, a2); a3 = fmaf(xk, w2.w, a3);
        }
        float4 r2; r2.x=a0; r2.y=a1; r2.z=a2; r2.w=a3;
        o2[h0>>2] = r2;
    }
}

// ---------- K-back: logits = xsum @ Wl + bl; out = log_softmax ----------
__global__ __launch_bounds__(256) void k_back(
    const float* __restrict__ xsum,
    const float* __restrict__ Wl,
    const float* __restrict__ bl,
    float* __restrict__ out,
    int n)
{
    __shared__ float sWl[1024];  // 64 x 16
    __shared__ float sbl[16];
    int tid = threadIdx.x;
    if (tid < 256) ((float4*)sWl)[tid] = ((const float4*)Wl)[tid];
    if (tid < 4)  ((float4*)sbl)[tid] = ((const float4*)bl)[tid];
    __syncthreads();
    int r = blockIdx.x * 256 + tid;
    if (r >= n) return;
    float x[64];
    const float4* px = (const float4*)(xsum + (long long)r * 64);
    #pragma unroll
    for (int i = 0; i < 16; ++i) {
        float4 v = px[i];
        x[4*i+0] = v.x; x[4*i+1] = v.y; x[4*i+2] = v.z; x[4*i+3] = v.w;
    }
    float lg[16];
    #pragma unroll 1
    for (int c0 = 0; c0 < 16; c0 += 4) {
        float4 bb = *(const float4*)(sbl + c0);
        float l0=bb.x, l1=bb.y, l2=bb.z, l3=bb.w;
        #pragma unroll
        for (int d = 0; d < 64; ++d) {
            float xd = x[d];
            float4 wl = *(const float4*)(sWl + d*16 + c0);
            l0 = fmaf(xd, wl.x, l0); l1 = fmaf(xd, wl.y, l1);
            l2 = fmaf(xd, wl.z, l2); l3 = fmaf(xd, wl.w, l3);
        }
        lg[c0]=l0; lg[c0+1]=l1; lg[c0+2]=l2; lg[c0+3]=l3;
    }
    float m = lg[0];
    #pragma unroll
    for (int c = 1; c < 16; ++c) m = fmaxf(m, lg[c]);
    float ssum = 0.f;
    #pragma unroll
    for (int c = 0; c < 16; ++c) ssum += __expf(lg[c] - m);
    float lse = m + __logf(ssum);
    float4* po = (float4*)(out + (long long)r * 16);
    #pragma unroll
    for (int c0 = 0; c0 < 16; c0 += 4) {
        float4 o;
        o.x = lg[c0+0]-lse; o.y = lg[c0+1]-lse;
        o.z = lg[c0+2]-lse; o.w = lg[c0+3]-lse;
        po[c0>>2] = o;
    }
}

// ---------- launch ----------
extern "C" void kernel_launch(void* const* d_in, const int* in_sizes, int n_in,
                              void* d_out, int out_size, void* d_ws, size_t ws_size,
                              hipStream_t stream)
{
    const int*   node_index = (const int*)d_in[0];
    const int*   edge_index = (const int*)d_in[1];
    const float* ew  = (const float*)d_in[2];
    const float* emb = (const float*)d_in[3];
    const float* W1  = (const float*)d_in[4];
    const float* b1  = (const float*)d_in[5];
    const float* W2  = (const float*)d_in[6];
    const float* b2  = (const float*)d_in[7];
    const float* Wf  = (const float*)d_in[8];
    const float* bfv = (const float*)d_in[9];
    const float* Wl  = (const float*)d_in[10];
    const float* bl  = (const float*)d_in[11];

    const int N = in_sizes[0];
    const int E = in_sizes[2];
    const int* srcp = edge_index;
    const int* dstp = edge_index + E;

    char* ws = (char*)d_ws;
    size_t off = 0;
    auto alloc = [&](size_t bytes) {
        void* p = ws + off;
        off += (bytes + 255) & ~size_t(255);
        return p;
    };
    float* deg    = (float*)alloc((size_t)N * 4);          // becomes dinv in-place
    int*   cnt    = (int*)  alloc((size_t)N * 4);
    int*   bsum   = (int*)  alloc(512 * 4);
    int*   rowptr = (int*)  alloc((size_t)(N + 1) * 4);
    int*   cursor = (int*)  alloc((size_t)N * 4);
    int2*  meta   = (int2*) alloc((size_t)E * 8);
    float* xw1    = (float*)alloc((size_t)N * 64 * 4);     // reused as xsum
    float* xf     = (float*)alloc((size_t)N * 64 * 4);
    float* x1     = (float*)alloc((size_t)N * 64 * 4);
    float* xw2    = (float*)alloc((size_t)N * 64 * 4);
    float* xsum   = xw1;   // xw1 dead after gather1

    int nb_nodes  = (N + 255) / 256;                        // 391 (must be <= 512 for scan)
    int nb_edges  = (E + 255) / 256;
    int nb_gather = (N + 3) / 4;                            // 4 waves (nodes) per block

    hipMemsetAsync(deg, 0, (size_t)N * 4, stream);
    hipMemsetAsync(cnt, 0, (size_t)N * 4, stream);
    k_deg_cnt<<<nb_edges, 256, 0, stream>>>(dstp, ew, deg, cnt, E);
    k_dinv<<<nb_nodes, 256, 0, stream>>>(deg, N);
    k_blocksum<<<nb_nodes, 256, 0, stream>>>(cnt, bsum, N);
    k_scan_bsum<<<1, 512, 0, stream>>>(bsum, nb_nodes);
    k_scan_apply<<<nb_nodes, 256, 0, stream>>>(cnt, bsum, rowptr, cursor, N);
    k_fill<<<nb_edges, 256, 0, stream>>>(srcp, dstp, ew, deg, cursor, meta, E);
    k_front<<<nb_nodes, 256, 0, stream>>>(node_index, emb, W1, Wf, bfv, xw1, xf, N);
    k_gather<false><<<nb_gather, 256, 0, stream>>>(meta, rowptr, deg, xw1, b1, nullptr, x1, N);
    k_mid<<<nb_nodes, 256, 0, stream>>>(xf, W2, xw2, N);
    k_gather<true><<<nb_gather, 256, 0, stream>>>(meta, rowptr, deg, xw2, b2, x1, xsum, N);
    k_back<<<nb_nodes, 256, 0, stream>>>(xsum, Wl, bl, (float*)d_out, N);
}

// Round 4
// 607.843 us; speedup vs baseline: 1.8234x; 1.2518x over previous
//
#include <hip/hip_runtime.h>
#include <math.h>

// ---------- helpers ----------
__device__ __forceinline__ float elu_f(float v) {
    return v > 0.f ? v : expm1f(v);
}

// ---------- K1: deg[dst] += ew ; cnt[dst] += 1 ----------
__global__ __launch_bounds__(256) void k_deg_cnt(const int* __restrict__ dst,
                                                 const float* __restrict__ ew,
                                                 float* __restrict__ deg,
                                                 int* __restrict__ cnt, int E) {
    int i = blockIdx.x * 256 + threadIdx.x;
    if (i < E) {
        int d = dst[i];
        unsafeAtomicAdd(&deg[d], ew[i]);
        atomicAdd(&cnt[d], 1);
    }
}

// ---------- K2: per-block sums of cnt + dinv = rsqrt(deg+1) fused ----------
__global__ __launch_bounds__(256) void k_blocksum_dinv(const int* __restrict__ cnt,
                                                       float* __restrict__ deg,
                                                       int* __restrict__ bsum, int n) {
    __shared__ int sm[256];
    int t = threadIdx.x;
    int i = blockIdx.x * 256 + t;
    int v = (i < n) ? cnt[i] : 0;
    sm[t] = v;
    if (i < n) deg[i] = rsqrtf(deg[i] + 1.0f);
    __syncthreads();
    for (int off = 128; off > 0; off >>= 1) {
        if (t < off) sm[t] += sm[t + off];
        __syncthreads();
    }
    if (t == 0) bsum[blockIdx.x] = sm[0];
}

// ---------- scan step 2: exclusive scan of block sums (single block, nb<=512) ----------
__global__ __launch_bounds__(512) void k_scan_bsum(int* __restrict__ bsum, int nb) {
    __shared__ int sm[512];
    int t = threadIdx.x;
    int v = (t < nb) ? bsum[t] : 0;
    sm[t] = v;
    __syncthreads();
    for (int off = 1; off < 512; off <<= 1) {
        int x = sm[t];
        int y = (t >= off) ? sm[t - off] : 0;
        __syncthreads();
        sm[t] = x + y;
        __syncthreads();
    }
    if (t < nb) bsum[t] = sm[t] - v;   // exclusive
}

// ---------- scan step 3: rowptr = blockoff + intra-block exclusive scan ----------
__global__ __launch_bounds__(256) void k_scan_apply(const int* __restrict__ cnt,
                                                    const int* __restrict__ bsum,
                                                    int* __restrict__ rowptr,
                                                    int* __restrict__ cursor, int n) {
    __shared__ int sm[256];
    int t = threadIdx.x;
    int i = blockIdx.x * 256 + t;
    int v = (i < n) ? cnt[i] : 0;
    sm[t] = v;
    __syncthreads();
    for (int off = 1; off < 256; off <<= 1) {
        int x = sm[t];
        int y = (t >= off) ? sm[t - off] : 0;
        __syncthreads();
        sm[t] = x + y;
        __syncthreads();
    }
    int excl = sm[t] - v + bsum[blockIdx.x];
    if (i < n) {
        rowptr[i] = excl;
        cursor[i] = excl;
        if (i == n - 1) rowptr[n] = excl + v;
    }
}

// ---------- K-fill: counting-sort edges by dst; meta = (src, norm) ----------
__global__ __launch_bounds__(256) void k_fill(const int* __restrict__ src,
                                              const int* __restrict__ dst,
                                              const float* __restrict__ ew,
                                              const float* __restrict__ dinv,
                                              int* __restrict__ cursor,
                                              int2* __restrict__ meta, int E) {
    int i = blockIdx.x * 256 + threadIdx.x;
    if (i >= E) return;
    int s = src[i], d = dst[i];
    float nrm = dinv[s] * ew[i] * dinv[d];
    int pos = atomicAdd(&cursor[d], 1);
    meta[pos] = make_int2(s, __float_as_int(nrm));
}

// ---------- K-front (fused): xw1 = emb[ni]@W1 ; xf = elu(emb[ni]@Wf+bf) (regs);
//                             xw2 = xf@W2 ----------
__global__ __launch_bounds__(256) void k_front(
    const int* __restrict__ node_index,
    const float* __restrict__ emb,
    const float* __restrict__ W1,
    const float* __restrict__ Wf,
    const float* __restrict__ bfv,
    const float* __restrict__ W2,
    float* __restrict__ xw1,
    float* __restrict__ xw2,
    int n)
{
    __shared__ float sW1[4096];
    __shared__ float sWf[4096];
    __shared__ float sW2[4096];
    __shared__ float sbf[64];
    int tid = threadIdx.x;
    for (int i = tid; i < 1024; i += 256) {
        ((float4*)sW1)[i] = ((const float4*)W1)[i];
        ((float4*)sWf)[i] = ((const float4*)Wf)[i];
        ((float4*)sW2)[i] = ((const float4*)W2)[i];
    }
    if (tid < 16) ((float4*)sbf)[tid] = ((const float4*)bfv)[tid];
    __syncthreads();
    int r = blockIdx.x * 256 + tid;
    if (r >= n) return;
    int idx = node_index[r];
    float x[64];
    const float4* xr = (const float4*)(emb + (size_t)idx * 64);
    #pragma unroll
    for (int i = 0; i < 16; ++i) {
        float4 v = xr[i];
        x[4*i+0] = v.x; x[4*i+1] = v.y; x[4*i+2] = v.z; x[4*i+3] = v.w;
    }
    float xf[64];
    float4* o1 = (float4*)(xw1 + (size_t)r * 64);
    // pass 1: xw1 (store) and xf (registers)
    #pragma unroll 1
    for (int h0 = 0; h0 < 64; h0 += 4) {
        float a0=0,a1=0,a2=0,a3=0, f0=0,f1=0,f2=0,f3=0;
        #pragma unroll
        for (int k = 0; k < 64; ++k) {
            float xk = x[k];
            float4 w1 = *(const float4*)(sW1 + k*64 + h0);  // broadcast, conflict-free
            float4 wf = *(const float4*)(sWf + k*64 + h0);
            a0 = fmaf(xk, w1.x, a0); a1 = fmaf(xk, w1.y, a1);
            a2 = fmaf(xk, w1.z, a2); a3 = fmaf(xk, w1.w, a3);
            f0 = fmaf(xk, wf.x, f0); f1 = fmaf(xk, wf.y, f1);
            f2 = fmaf(xk, wf.z, f2); f3 = fmaf(xk, wf.w, f3);
        }
        float4 r1; r1.x=a0; r1.y=a1; r1.z=a2; r1.w=a3;
        o1[h0>>2] = r1;
        float4 b = *(const float4*)(sbf + h0);
        xf[h0+0] = elu_f(f0 + b.x); xf[h0+1] = elu_f(f1 + b.y);
        xf[h0+2] = elu_f(f2 + b.z); xf[h0+3] = elu_f(f3 + b.w);
    }
    // pass 2: xw2 = xf @ W2
    float4* o2 = (float4*)(xw2 + (size_t)r * 64);
    #pragma unroll 1
    for (int h0 = 0; h0 < 64; h0 += 4) {
        float a0=0,a1=0,a2=0,a3=0;
        #pragma unroll
        for (int k = 0; k < 64; ++k) {
            float xk = xf[k];
            float4 w2 = *(const float4*)(sW2 + k*64 + h0);
            a0 = fmaf(xk, w2.x, a0); a1 = fmaf(xk, w2.y, a1);
            a2 = fmaf(xk, w2.z, a2); a3 = fmaf(xk, w2.w, a3);
        }
        float4 r2; r2.x=a0; r2.y=a1; r2.z=a2; r2.w=a3;
        o2[h0>>2] = r2;
    }
}

// ---------- K-gather: one wave per dst node, lane = feature dim, unroll-8 MLP ----------
// MODE 0: x1buf[d] = elu(agg + self + bias)
// MODE 1: x = x1buf[d] + elu(agg + self + bias); logits = x@Wl + bl;
//         out[d] = log_softmax(logits)   (fused via 64-lane shuffle reduce)
template<int MODE>
__global__ __launch_bounds__(256) void k_gather(
    const int2* __restrict__ meta,
    const int*  __restrict__ rowptr,
    const float* __restrict__ dinv,
    const float* __restrict__ xw,
    const float* __restrict__ bias,
    float* __restrict__ x1buf,
    const float* __restrict__ Wl,
    const float* __restrict__ bl,
    float* __restrict__ outp,
    int n)
{
    int lane = threadIdx.x & 63;
    int d = __builtin_amdgcn_readfirstlane(blockIdx.x * 4 + (threadIdx.x >> 6));
    if (d >= n) return;
    float di = dinv[d];
    float acc = xw[(size_t)d * 64 + lane] * di * di;   // self-loop term
    int e0 = rowptr[d], e1 = rowptr[d + 1];
    int e = e0;
    #pragma unroll 1
    for (; e + 8 <= e1; e += 8) {
        int2 m0 = meta[e+0]; int2 m1 = meta[e+1];
        int2 m2 = meta[e+2]; int2 m3 = meta[e+3];
        int2 m4 = meta[e+4]; int2 m5 = meta[e+5];
        int2 m6 = meta[e+6]; int2 m7 = meta[e+7];
        float v0 = xw[(size_t)m0.x * 64 + lane];
        float v1 = xw[(size_t)m1.x * 64 + lane];
        float v2 = xw[(size_t)m2.x * 64 + lane];
        float v3 = xw[(size_t)m3.x * 64 + lane];
        float v4 = xw[(size_t)m4.x * 64 + lane];
        float v5 = xw[(size_t)m5.x * 64 + lane];
        float v6 = xw[(size_t)m6.x * 64 + lane];
        float v7 = xw[(size_t)m7.x * 64 + lane];
        acc = fmaf(v0, __int_as_float(m0.y), acc);
        acc = fmaf(v1, __int_as_float(m1.y), acc);
        acc = fmaf(v2, __int_as_float(m2.y), acc);
        acc = fmaf(v3, __int_as_float(m3.y), acc);
        acc = fmaf(v4, __int_as_float(m4.y), acc);
        acc = fmaf(v5, __int_as_float(m5.y), acc);
        acc = fmaf(v6, __int_as_float(m6.y), acc);
        acc = fmaf(v7, __int_as_float(m7.y), acc);
    }
    if (e + 4 <= e1) {
        int2 m0 = meta[e+0]; int2 m1 = meta[e+1];
        int2 m2 = meta[e+2]; int2 m3 = meta[e+3];
        float v0 = xw[(size_t)m0.x * 64 + lane];
        float v1 = xw[(size_t)m1.x * 64 + lane];
        float v2 = xw[(size_t)m2.x * 64 + lane];
        float v3 = xw[(size_t)m3.x * 64 + lane];
        acc = fmaf(v0, __int_as_float(m0.y), acc);
        acc = fmaf(v1, __int_as_float(m1.y), acc);
        acc = fmaf(v2, __int_as_float(m2.y), acc);
        acc = fmaf(v3, __int_as_float(m3.y), acc);
        e += 4;
    }
    #pragma unroll 1
    for (; e < e1; ++e) {
        int2 m = meta[e];
        acc = fmaf(xw[(size_t)m.x * 64 + lane], __int_as_float(m.y), acc);
    }
    float r = elu_f(acc + bias[lane]);
    if (MODE == 0) {
        x1buf[(size_t)d * 64 + lane] = r;
    } else {
        float xv = r + x1buf[(size_t)d * 64 + lane];
        // per-lane row of Wl: [64][16] row-major
        const float4* wrow = (const float4*)(Wl + lane * 16);
        float4 w0 = wrow[0], w1 = wrow[1], w2 = wrow[2], w3 = wrow[3];
        float p[16];
        p[ 0]=xv*w0.x; p[ 1]=xv*w0.y; p[ 2]=xv*w0.z; p[ 3]=xv*w0.w;
        p[ 4]=xv*w1.x; p[ 5]=xv*w1.y; p[ 6]=xv*w1.z; p[ 7]=xv*w1.w;
        p[ 8]=xv*w2.x; p[ 9]=xv*w2.y; p[10]=xv*w2.z; p[11]=xv*w2.w;
        p[12]=xv*w3.x; p[13]=xv*w3.y; p[14]=xv*w3.z; p[15]=xv*w3.w;
        #pragma unroll
        for (int off = 32; off >= 1; off >>= 1) {
            #pragma unroll
            for (int c = 0; c < 16; ++c)
                p[c] += __shfl_xor(p[c], off, 64);
        }
        float4 bb0 = ((const float4*)bl)[0];
        float4 bb1 = ((const float4*)bl)[1];
        float4 bb2 = ((const float4*)bl)[2];
        float4 bb3 = ((const float4*)bl)[3];
        p[ 0]+=bb0.x; p[ 1]+=bb0.y; p[ 2]+=bb0.z; p[ 3]+=bb0.w;
        p[ 4]+=bb1.x; p[ 5]+=bb1.y; p[ 6]+=bb1.z; p[ 7]+=bb1.w;
        p[ 8]+=bb2.x; p[ 9]+=bb2.y; p[10]+=bb2.z; p[11]+=bb2.w;
        p[12]+=bb3.x; p[13]+=bb3.y; p[14]+=bb3.z; p[15]+=bb3.w;
        float m = p[0];
        #pragma unroll
        for (int c = 1; c < 16; ++c) m = fmaxf(m, p[c]);
        float es = 0.f;
        #pragma unroll
        for (int c = 0; c < 16; ++c) es += __expf(p[c] - m);
        float lse = m + __logf(es);
        if (lane == 0) {
            float4* po = (float4*)(outp + (size_t)d * 16);
            po[0] = make_float4(p[ 0]-lse, p[ 1]-lse, p[ 2]-lse, p[ 3]-lse);
            po[1] = make_float4(p[ 4]-lse, p[ 5]-lse, p[ 6]-lse, p[ 7]-lse);
            po[2] = make_float4(p[ 8]-lse, p[ 9]-lse, p[10]-lse, p[11]-lse);
            po[3] = make_float4(p[12]-lse, p[13]-lse, p[14]-lse, p[15]-lse);
        }
    }
}

// ---------- launch ----------
extern "C" void kernel_launch(void* const* d_in, const int* in_sizes, int n_in,
                              void* d_out, int out_size, void* d_ws, size_t ws_size,
                              hipStream_t stream)
{
    const int*   node_index = (const int*)d_in[0];
    const int*   edge_index = (const int*)d_in[1];
    const float* ew  = (const float*)d_in[2];
    const float* emb = (const float*)d_in[3];
    const float* W1  = (const float*)d_in[4];
    const float* b1  = (const float*)d_in[5];
    const float* W2  = (const float*)d_in[6];
    const float* b2  = (const float*)d_in[7];
    const float* Wf  = (const float*)d_in[8];
    const float* bfv = (const float*)d_in[9];
    const float* Wl  = (const float*)d_in[10];
    const float* bl  = (const float*)d_in[11];

    const int N = in_sizes[0];
    const int E = in_sizes[2];
    const int* srcp = edge_index;
    const int* dstp = edge_index + E;

    char* ws = (char*)d_ws;
    size_t off = 0;
    auto alloc = [&](size_t bytes) {
        void* p = ws + off;
        off += (bytes + 255) & ~size_t(255);
        return p;
    };
    float* deg    = (float*)alloc((size_t)N * 4);          // becomes dinv in-place
    int*   cnt    = (int*)  alloc((size_t)N * 4);
    int*   bsum   = (int*)  alloc(512 * 4);
    int*   rowptr = (int*)  alloc((size_t)(N + 1) * 4);
    int*   cursor = (int*)  alloc((size_t)N * 4);
    int2*  meta   = (int2*) alloc((size_t)E * 8);
    float* xw1    = (float*)alloc((size_t)N * 64 * 4);
    float* xw2    = (float*)alloc((size_t)N * 64 * 4);
    float* x1     = (float*)alloc((size_t)N * 64 * 4);

    int nb_nodes  = (N + 255) / 256;                        // 391 (<=512 for scan)
    int nb_edges  = (E + 255) / 256;
    int nb_gather = (N + 3) / 4;                            // 4 waves (nodes) per block

    hipMemsetAsync(deg, 0, (size_t)N * 4, stream);
    hipMemsetAsync(cnt, 0, (size_t)N * 4, stream);
    k_deg_cnt<<<nb_edges, 256, 0, stream>>>(dstp, ew, deg, cnt, E);
    k_blocksum_dinv<<<nb_nodes, 256, 0, stream>>>(cnt, deg, bsum, N);
    k_scan_bsum<<<1, 512, 0, stream>>>(bsum, nb_nodes);
    k_scan_apply<<<nb_nodes, 256, 0, stream>>>(cnt, bsum, rowptr, cursor, N);
    k_fill<<<nb_edges, 256, 0, stream>>>(srcp, dstp, ew, deg, cursor, meta, E);
    k_front<<<nb_nodes, 256, 0, stream>>>(node_index, emb, W1, Wf, bfv, W2, xw1, xw2, N);
    k_gather<0><<<nb_gather, 256, 0, stream>>>(meta, rowptr, deg, xw1, b1, x1,
                                               nullptr, nullptr, nullptr, N);
    k_gather<1><<<nb_gather, 256, 0, stream>>>(meta, rowptr, deg, xw2, b2, x1,
                                               Wl, bl, (float*)d_out, N);
}

// Round 5
// 453.246 us; speedup vs baseline: 2.4453x; 1.3411x over previous
//
#include <hip/hip_runtime.h>
#include <math.h>

#define PACK     67108864.0              // 2^26
#define PACK_INV 1.4901161193847656e-08  // 2^-26

// ---------- helpers ----------
__device__ __forceinline__ float elu_f(float v) {
    return v > 0.f ? v : expm1f(v);
}

// ---------- K1: packed[dst] += ew + 2^26 ; rank[e] = previous count ----------
__global__ __launch_bounds__(256) void k_hist(const int* __restrict__ dst,
                                              const float* __restrict__ ew,
                                              double* __restrict__ packed,
                                              int* __restrict__ rank, int E) {
    int i = blockIdx.x * 256 + threadIdx.x;
    if (i < E) {
        double old = unsafeAtomicAdd(&packed[dst[i]], (double)ew[i] + PACK);
        rank[i] = (int)(old * PACK_INV);   // floor: frac part < 2^-20
    }
}

// ---------- K2: decode packed -> dinv + cnt ; per-block sums of cnt ----------
__global__ __launch_bounds__(256) void k_decode_blocksum(
    const double* __restrict__ packed,
    float* __restrict__ dinv,
    int* __restrict__ cnt,
    int* __restrict__ bsum, int n)
{
    __shared__ int sm[256];
    int t = threadIdx.x;
    int i = blockIdx.x * 256 + t;
    int v = 0;
    if (i < n) {
        double val = packed[i];
        double c = floor(val * PACK_INV);
        v = (int)c;
        float deg = (float)(val - c * PACK);
        dinv[i] = rsqrtf(deg + 1.0f);
        cnt[i] = v;
    }
    sm[t] = v;
    __syncthreads();
    for (int off = 128; off > 0; off >>= 1) {
        if (t < off) sm[t] += sm[t + off];
        __syncthreads();
    }
    if (t == 0) bsum[blockIdx.x] = sm[0];
}

// ---------- scan step 2: exclusive scan of block sums (single block, nb<=512) ----------
__global__ __launch_bounds__(512) void k_scan_bsum(int* __restrict__ bsum, int nb) {
    __shared__ int sm[512];
    int t = threadIdx.x;
    int v = (t < nb) ? bsum[t] : 0;
    sm[t] = v;
    __syncthreads();
    for (int off = 1; off < 512; off <<= 1) {
        int x = sm[t];
        int y = (t >= off) ? sm[t - off] : 0;
        __syncthreads();
        sm[t] = x + y;
        __syncthreads();
    }
    if (t < nb) bsum[t] = sm[t] - v;   // exclusive
}

// ---------- scan step 3: rowptr = blockoff + intra-block exclusive scan ----------
__global__ __launch_bounds__(256) void k_scan_apply(const int* __restrict__ cnt,
                                                    const int* __restrict__ bsum,
                                                    int* __restrict__ rowptr, int n) {
    __shared__ int sm[256];
    int t = threadIdx.x;
    int i = blockIdx.x * 256 + t;
    int v = (i < n) ? cnt[i] : 0;
    sm[t] = v;
    __syncthreads();
    for (int off = 1; off < 256; off <<= 1) {
        int x = sm[t];
        int y = (t >= off) ? sm[t - off] : 0;
        __syncthreads();
        sm[t] = x + y;
        __syncthreads();
    }
    int excl = sm[t] - v + bsum[blockIdx.x];
    if (i < n) {
        rowptr[i] = excl;
        if (i == n - 1) rowptr[n] = excl + v;
    }
}

// ---------- K-fill (atomic-free): meta[rowptr[dst]+rank] = (src, norm) ----------
__global__ __launch_bounds__(256) void k_fill(const int* __restrict__ src,
                                              const int* __restrict__ dst,
                                              const float* __restrict__ ew,
                                              const int* __restrict__ rank,
                                              const float* __restrict__ dinv,
                                              const int* __restrict__ rowptr,
                                              int2* __restrict__ meta, int E) {
    int i = blockIdx.x * 256 + threadIdx.x;
    if (i >= E) return;
    int s = src[i], d = dst[i];
    float nrm = dinv[s] * ew[i] * dinv[d];
    int pos = rowptr[d] + rank[i];
    meta[pos] = make_int2(s, __float_as_int(nrm));
}

// ---------- K-front (fused): xw1 = emb[ni]@W1 ; xf = elu(emb[ni]@Wf+bf) (regs);
//                             xw2 = xf@W2 ----------
__global__ __launch_bounds__(256) void k_front(
    const int* __restrict__ node_index,
    const float* __restrict__ emb,
    const float* __restrict__ W1,
    const float* __restrict__ Wf,
    const float* __restrict__ bfv,
    const float* __restrict__ W2,
    float* __restrict__ xw1,
    float* __restrict__ xw2,
    int n)
{
    __shared__ float sW1[4096];
    __shared__ float sWf[4096];
    __shared__ float sW2[4096];
    __shared__ float sbf[64];
    int tid = threadIdx.x;
    for (int i = tid; i < 1024; i += 256) {
        ((float4*)sW1)[i] = ((const float4*)W1)[i];
        ((float4*)sWf)[i] = ((const float4*)Wf)[i];
        ((float4*)sW2)[i] = ((const float4*)W2)[i];
    }
    if (tid < 16) ((float4*)sbf)[tid] = ((const float4*)bfv)[tid];
    __syncthreads();
    int r = blockIdx.x * 256 + tid;
    if (r >= n) return;
    int idx = node_index[r];
    float x[64];
    const float4* xr = (const float4*)(emb + (size_t)idx * 64);
    #pragma unroll
    for (int i = 0; i < 16; ++i) {
        float4 v = xr[i];
        x[4*i+0] = v.x; x[4*i+1] = v.y; x[4*i+2] = v.z; x[4*i+3] = v.w;
    }
    float xf[64];
    float4* o1 = (float4*)(xw1 + (size_t)r * 64);
    // pass 1: xw1 (store) and xf (registers)
    #pragma unroll 1
    for (int h0 = 0; h0 < 64; h0 += 4) {
        float a0=0,a1=0,a2=0,a3=0, f0=0,f1=0,f2=0,f3=0;
        #pragma unroll
        for (int k = 0; k < 64; ++k) {
            float xk = x[k];
            float4 w1 = *(const float4*)(sW1 + k*64 + h0);  // broadcast, conflict-free
            float4 wf = *(const float4*)(sWf + k*64 + h0);
            a0 = fmaf(xk, w1.x, a0); a1 = fmaf(xk, w1.y, a1);
            a2 = fmaf(xk, w1.z, a2); a3 = fmaf(xk, w1.w, a3);
            f0 = fmaf(xk, wf.x, f0); f1 = fmaf(xk, wf.y, f1);
            f2 = fmaf(xk, wf.z, f2); f3 = fmaf(xk, wf.w, f3);
        }
        float4 r1; r1.x=a0; r1.y=a1; r1.z=a2; r1.w=a3;
        o1[h0>>2] = r1;
        float4 b = *(const float4*)(sbf + h0);
        xf[h0+0] = elu_f(f0 + b.x); xf[h0+1] = elu_f(f1 + b.y);
        xf[h0+2] = elu_f(f2 + b.z); xf[h0+3] = elu_f(f3 + b.w);
    }
    // pass 2: xw2 = xf @ W2
    float4* o2 = (float4*)(xw2 + (size_t)r * 64);
    #pragma unroll 1
    for (int h0 = 0; h0 < 64; h0 += 4) {
        float a0=0,a1=0,a2=0,a3=0;
        #pragma unroll
        for (int k = 0; k < 64; ++k) {
            float xk = xf[k];
            float4 w2 = *(const float4*)(sW2 + k*64 + h0);
            a0 = fmaf(xk, w2.x, a0); a1 = fmaf(xk, w2.y, a1);
            a2 = fmaf(xk, w2.z, a2); a3 = fmaf(xk, w2.w, a3);
        }
        float4 r2; r2.x=a0; r2.y=a1; r2.z=a2; r2.w=a3;
        o2[h0>>2] = r2;
    }
}

// ---------- K-gather (fused both convs + classifier + log_softmax) ----------
// one wave per dst node, lane = feature dim; unroll-4 => 8 row loads in flight
__global__ __launch_bounds__(256) void k_gather(
    const int2* __restrict__ meta,
    const int*  __restrict__ rowptr,
    const float* __restrict__ dinv,
    const float* __restrict__ xw1,
    const float* __restrict__ xw2,
    const float* __restrict__ b1,
    const float* __restrict__ b2,
    const float* __restrict__ Wl,
    const float* __restrict__ bl,
    float* __restrict__ outp,
    int n)
{
    int lane = threadIdx.x & 63;
    int d = __builtin_amdgcn_readfirstlane(blockIdx.x * 4 + (threadIdx.x >> 6));
    if (d >= n) return;
    float di = dinv[d];
    float di2 = di * di;
    float acc1 = xw1[(size_t)d * 64 + lane] * di2;   // self-loop terms
    float acc2 = xw2[(size_t)d * 64 + lane] * di2;
    int e = rowptr[d], e1 = rowptr[d + 1];
    #pragma unroll 1
    for (; e + 4 <= e1; e += 4) {
        int2 m0 = meta[e+0]; int2 m1 = meta[e+1];
        int2 m2 = meta[e+2]; int2 m3 = meta[e+3];
        float a0 = xw1[(size_t)m0.x * 64 + lane];
        float a1 = xw1[(size_t)m1.x * 64 + lane];
        float a2 = xw1[(size_t)m2.x * 64 + lane];
        float a3 = xw1[(size_t)m3.x * 64 + lane];
        float c0 = xw2[(size_t)m0.x * 64 + lane];
        float c1 = xw2[(size_t)m1.x * 64 + lane];
        float c2 = xw2[(size_t)m2.x * 64 + lane];
        float c3 = xw2[(size_t)m3.x * 64 + lane];
        acc1 = fmaf(a0, __int_as_float(m0.y), acc1);
        acc1 = fmaf(a1, __int_as_float(m1.y), acc1);
        acc1 = fmaf(a2, __int_as_float(m2.y), acc1);
        acc1 = fmaf(a3, __int_as_float(m3.y), acc1);
        acc2 = fmaf(c0, __int_as_float(m0.y), acc2);
        acc2 = fmaf(c1, __int_as_float(m1.y), acc2);
        acc2 = fmaf(c2, __int_as_float(m2.y), acc2);
        acc2 = fmaf(c3, __int_as_float(m3.y), acc2);
    }
    #pragma unroll 1
    for (; e < e1; ++e) {
        int2 m = meta[e];
        float nrm = __int_as_float(m.y);
        acc1 = fmaf(xw1[(size_t)m.x * 64 + lane], nrm, acc1);
        acc2 = fmaf(xw2[(size_t)m.x * 64 + lane], nrm, acc2);
    }
    float r1 = elu_f(acc1 + b1[lane]);
    float xv = r1 + elu_f(acc2 + b2[lane]);
    // logits: per-lane row of Wl [64][16], butterfly reduce across 64 lanes
    const float4* wrow = (const float4*)(Wl + lane * 16);
    float4 w0 = wrow[0], w1 = wrow[1], w2 = wrow[2], w3 = wrow[3];
    float p[16];
    p[ 0]=xv*w0.x; p[ 1]=xv*w0.y; p[ 2]=xv*w0.z; p[ 3]=xv*w0.w;
    p[ 4]=xv*w1.x; p[ 5]=xv*w1.y; p[ 6]=xv*w1.z; p[ 7]=xv*w1.w;
    p[ 8]=xv*w2.x; p[ 9]=xv*w2.y; p[10]=xv*w2.z; p[11]=xv*w2.w;
    p[12]=xv*w3.x; p[13]=xv*w3.y; p[14]=xv*w3.z; p[15]=xv*w3.w;
    #pragma unroll
    for (int off = 32; off >= 1; off >>= 1) {
        #pragma unroll
        for (int c = 0; c < 16; ++c)
            p[c] += __shfl_xor(p[c], off, 64);
    }
    float4 bb0 = ((const float4*)bl)[0];
    float4 bb1 = ((const float4*)bl)[1];
    float4 bb2 = ((const float4*)bl)[2];
    float4 bb3 = ((const float4*)bl)[3];
    p[ 0]+=bb0.x; p[ 1]+=bb0.y; p[ 2]+=bb0.z; p[ 3]+=bb0.w;
    p[ 4]+=bb1.x; p[ 5]+=bb1.y; p[ 6]+=bb1.z; p[ 7]+=bb1.w;
    p[ 8]+=bb2.x; p[ 9]+=bb2.y; p[10]+=bb2.z; p[11]+=bb2.w;
    p[12]+=bb3.x; p[13]+=bb3.y; p[14]+=bb3.z; p[15]+=bb3.w;
    float m = p[0];
    #pragma unroll
    for (int c = 1; c < 16; ++c) m = fmaxf(m, p[c]);
    float es = 0.f;
    #pragma unroll
    for (int c = 0; c < 16; ++c) es += __expf(p[c] - m);
    float lse = m + __logf(es);
    if (lane == 0) {
        float4* po = (float4*)(outp + (size_t)d * 16);
        po[0] = make_float4(p[ 0]-lse, p[ 1]-lse, p[ 2]-lse, p[ 3]-lse);
        po[1] = make_float4(p[ 4]-lse, p[ 5]-lse, p[ 6]-lse, p[ 7]-lse);
        po[2] = make_float4(p[ 8]-lse, p[ 9]-lse, p[10]-lse, p[11]-lse);
        po[3] = make_float4(p[12]-lse, p[13]-lse, p[14]-lse, p[15]-lse);
    }
}

// ---------- launch ----------
extern "C" void kernel_launch(void* const* d_in, const int* in_sizes, int n_in,
                              void* d_out, int out_size, void* d_ws, size_t ws_size,
                              hipStream_t stream)
{
    const int*   node_index = (const int*)d_in[0];
    const int*   edge_index = (const int*)d_in[1];
    const float* ew  = (const float*)d_in[2];
    const float* emb = (const float*)d_in[3];
    const float* W1  = (const float*)d_in[4];
    const float* b1  = (const float*)d_in[5];
    const float* W2  = (const float*)d_in[6];
    const float* b2  = (const float*)d_in[7];
    const float* Wf  = (const float*)d_in[8];
    const float* bfv = (const float*)d_in[9];
    const float* Wl  = (const float*)d_in[10];
    const float* bl  = (const float*)d_in[11];

    const int N = in_sizes[0];
    const int E = in_sizes[2];
    const int* srcp = edge_index;
    const int* dstp = edge_index + E;

    char* ws = (char*)d_ws;
    size_t off = 0;
    auto alloc = [&](size_t bytes) {
        void* p = ws + off;
        off += (bytes + 255) & ~size_t(255);
        return p;
    };
    double* packed = (double*)alloc((size_t)N * 8);
    int*    rank   = (int*)   alloc((size_t)E * 4);
    int*    cnt    = (int*)   alloc((size_t)N * 4);
    int*    bsum   = (int*)   alloc(512 * 4);
    int*    rowptr = (int*)   alloc((size_t)(N + 1) * 4);
    float*  dinv   = (float*) alloc((size_t)N * 4);
    int2*   meta   = (int2*)  alloc((size_t)E * 8);
    float*  xw1    = (float*) alloc((size_t)N * 64 * 4);
    float*  xw2    = (float*) alloc((size_t)N * 64 * 4);

    int nb_nodes  = (N + 255) / 256;                        // 391 (<=512 for scan)
    int nb_edges  = (E + 255) / 256;
    int nb_gather = (N + 3) / 4;                            // 4 waves (nodes) per block

    hipMemsetAsync(packed, 0, (size_t)N * 8, stream);
    k_hist<<<nb_edges, 256, 0, stream>>>(dstp, ew, packed, rank, E);
    k_decode_blocksum<<<nb_nodes, 256, 0, stream>>>(packed, dinv, cnt, bsum, N);
    k_scan_bsum<<<1, 512, 0, stream>>>(bsum, nb_nodes);
    k_scan_apply<<<nb_nodes, 256, 0, stream>>>(cnt, bsum, rowptr, N);
    k_fill<<<nb_edges, 256, 0, stream>>>(srcp, dstp, ew, rank, dinv, rowptr, meta, E);
    k_front<<<nb_nodes, 256, 0, stream>>>(node_index, emb, W1, Wf, bfv, W2, xw1, xw2, N);
    k_gather<<<nb_gather, 256, 0, stream>>>(meta, rowptr, dinv, xw1, xw2,
                                            b1, b2, Wl, bl, (float*)d_out, N);
}

// Round 6
// 439.453 us; speedup vs baseline: 2.5221x; 1.0314x over previous
//
#include <hip/hip_runtime.h>
#include <hip/hip_fp16.h>
#include <math.h>

#define PACK     67108864.0              // 2^26
#define PACK_INV 1.4901161193847656e-08  // 2^-26

// ---------- helpers ----------
__device__ __forceinline__ float elu_f(float v) {
    return v > 0.f ? v : expm1f(v);
}
__device__ __forceinline__ unsigned pack2h(float a, float b) {
    __half2 h = __floats2half2_rn(a, b);
    return *(unsigned*)&h;
}

// ---------- K1: packed[dst] += ew + 2^26 ; rank[e] = previous count ----------
__global__ __launch_bounds__(256) void k_hist(const int* __restrict__ dst,
                                              const float* __restrict__ ew,
                                              double* __restrict__ packed,
                                              int* __restrict__ rank, int E) {
    int i = blockIdx.x * 256 + threadIdx.x;
    if (i < E) {
        double old = unsafeAtomicAdd(&packed[dst[i]], (double)ew[i] + PACK);
        rank[i] = (int)(old * PACK_INV);   // floor: frac part < 2^-20
    }
}

// ---------- K2: decode packed -> dinv + cnt ; per-block sums of cnt ----------
__global__ __launch_bounds__(256) void k_decode_blocksum(
    const double* __restrict__ packed,
    float* __restrict__ dinv,
    int* __restrict__ cnt,
    int* __restrict__ bsum, int n)
{
    __shared__ int sm[256];
    int t = threadIdx.x;
    int i = blockIdx.x * 256 + t;
    int v = 0;
    if (i < n) {
        double val = packed[i];
        double c = floor(val * PACK_INV);
        v = (int)c;
        float deg = (float)(val - c * PACK);
        dinv[i] = rsqrtf(deg + 1.0f);
        cnt[i] = v;
    }
    sm[t] = v;
    __syncthreads();
    for (int off = 128; off > 0; off >>= 1) {
        if (t < off) sm[t] += sm[t + off];
        __syncthreads();
    }
    if (t == 0) bsum[blockIdx.x] = sm[0];
}

// ---------- scan step 2: exclusive scan of block sums (single block, nb<=512) ----------
__global__ __launch_bounds__(512) void k_scan_bsum(int* __restrict__ bsum, int nb) {
    __shared__ int sm[512];
    int t = threadIdx.x;
    int v = (t < nb) ? bsum[t] : 0;
    sm[t] = v;
    __syncthreads();
    for (int off = 1; off < 512; off <<= 1) {
        int x = sm[t];
        int y = (t >= off) ? sm[t - off] : 0;
        __syncthreads();
        sm[t] = x + y;
        __syncthreads();
    }
    if (t < nb) bsum[t] = sm[t] - v;   // exclusive
}

// ---------- scan step 3: rowptr = blockoff + intra-block exclusive scan ----------
__global__ __launch_bounds__(256) void k_scan_apply(const int* __restrict__ cnt,
                                                    const int* __restrict__ bsum,
                                                    int* __restrict__ rowptr, int n) {
    __shared__ int sm[256];
    int t = threadIdx.x;
    int i = blockIdx.x * 256 + t;
    int v = (i < n) ? cnt[i] : 0;
    sm[t] = v;
    __syncthreads();
    for (int off = 1; off < 256; off <<= 1) {
        int x = sm[t];
        int y = (t >= off) ? sm[t - off] : 0;
        __syncthreads();
        sm[t] = x + y;
        __syncthreads();
    }
    int excl = sm[t] - v + bsum[blockIdx.x];
    if (i < n) {
        rowptr[i] = excl;
        if (i == n - 1) rowptr[n] = excl + v;
    }
}

// ---------- K-fill (atomic-free): meta[rowptr[dst]+rank] = (src, norm) ----------
__global__ __launch_bounds__(256) void k_fill(const int* __restrict__ src,
                                              const int* __restrict__ dst,
                                              const float* __restrict__ ew,
                                              const int* __restrict__ rank,
                                              const float* __restrict__ dinv,
                                              const int* __restrict__ rowptr,
                                              int2* __restrict__ meta, int E) {
    int i = blockIdx.x * 256 + threadIdx.x;
    if (i >= E) return;
    int s = src[i], d = dst[i];
    float nrm = dinv[s] * ew[i] * dinv[d];
    int pos = rowptr[d] + rank[i];
    meta[pos] = make_int2(s, __float_as_int(nrm));
}

// ---------- K-front (fused): xw1 = emb[ni]@W1 ; xf = elu(emb[ni]@Wf+bf) (regs);
//                             xw2 = xf@W2 ; stores fp16 ----------
__global__ __launch_bounds__(256) void k_front(
    const int* __restrict__ node_index,
    const float* __restrict__ emb,
    const float* __restrict__ W1,
    const float* __restrict__ Wf,
    const float* __restrict__ bfv,
    const float* __restrict__ W2,
    __half* __restrict__ xw1h,
    __half* __restrict__ xw2h,
    int n)
{
    __shared__ float sW1[4096];
    __shared__ float sWf[4096];
    __shared__ float sW2[4096];
    __shared__ float sbf[64];
    int tid = threadIdx.x;
    for (int i = tid; i < 1024; i += 256) {
        ((float4*)sW1)[i] = ((const float4*)W1)[i];
        ((float4*)sWf)[i] = ((const float4*)Wf)[i];
        ((float4*)sW2)[i] = ((const float4*)W2)[i];
    }
    if (tid < 16) ((float4*)sbf)[tid] = ((const float4*)bfv)[tid];
    __syncthreads();
    int r = blockIdx.x * 256 + tid;
    if (r >= n) return;
    int idx = node_index[r];
    float x[64];
    const float4* xr = (const float4*)(emb + (size_t)idx * 64);
    #pragma unroll
    for (int i = 0; i < 16; ++i) {
        float4 v = xr[i];
        x[4*i+0] = v.x; x[4*i+1] = v.y; x[4*i+2] = v.z; x[4*i+3] = v.w;
    }
    float xf[64];
    uint2* o1 = (uint2*)(xw1h + (size_t)r * 64);
    // pass 1: xw1 (fp16 store) and xf (registers)
    #pragma unroll 1
    for (int h0 = 0; h0 < 64; h0 += 4) {
        float a0=0,a1=0,a2=0,a3=0, f0=0,f1=0,f2=0,f3=0;
        #pragma unroll
        for (int k = 0; k < 64; ++k) {
            float xk = x[k];
            float4 w1 = *(const float4*)(sW1 + k*64 + h0);  // broadcast, conflict-free
            float4 wf = *(const float4*)(sWf + k*64 + h0);
            a0 = fmaf(xk, w1.x, a0); a1 = fmaf(xk, w1.y, a1);
            a2 = fmaf(xk, w1.z, a2); a3 = fmaf(xk, w1.w, a3);
            f0 = fmaf(xk, wf.x, f0); f1 = fmaf(xk, wf.y, f1);
            f2 = fmaf(xk, wf.z, f2); f3 = fmaf(xk, wf.w, f3);
        }
        o1[h0>>2] = make_uint2(pack2h(a0, a1), pack2h(a2, a3));
        float4 b = *(const float4*)(sbf + h0);
        xf[h0+0] = elu_f(f0 + b.x); xf[h0+1] = elu_f(f1 + b.y);
        xf[h0+2] = elu_f(f2 + b.z); xf[h0+3] = elu_f(f3 + b.w);
    }
    // pass 2: xw2 = xf @ W2 (fp16 store)
    uint2* o2 = (uint2*)(xw2h + (size_t)r * 64);
    #pragma unroll 1
    for (int h0 = 0; h0 < 64; h0 += 4) {
        float a0=0,a1=0,a2=0,a3=0;
        #pragma unroll
        for (int k = 0; k < 64; ++k) {
            float xk = xf[k];
            float4 w2 = *(const float4*)(sW2 + k*64 + h0);
            a0 = fmaf(xk, w2.x, a0); a1 = fmaf(xk, w2.y, a1);
            a2 = fmaf(xk, w2.z, a2); a3 = fmaf(xk, w2.w, a3);
        }
        o2[h0>>2] = make_uint2(pack2h(a0, a1), pack2h(a2, a3));
    }
}

// ---------- K-gather (fused both convs + classifier + log_softmax) ----------
// one wave per dst node, lane = feature dim; unroll-8 => 16 row loads in flight
__global__ __launch_bounds__(256) void k_gather(
    const int2* __restrict__ meta,
    const int*  __restrict__ rowptr,
    const float* __restrict__ dinv,
    const __half* __restrict__ xw1h,
    const __half* __restrict__ xw2h,
    const float* __restrict__ b1,
    const float* __restrict__ b2,
    const float* __restrict__ Wl,
    const float* __restrict__ bl,
    float* __restrict__ outp,
    int n)
{
    int lane = threadIdx.x & 63;
    int d = __builtin_amdgcn_readfirstlane(blockIdx.x * 4 + (threadIdx.x >> 6));
    if (d >= n) return;
    float di = dinv[d];
    float di2 = di * di;
    float acc1 = __half2float(xw1h[(size_t)d * 64 + lane]) * di2;  // self-loop
    float acc2 = __half2float(xw2h[(size_t)d * 64 + lane]) * di2;
    int e = rowptr[d], e1 = rowptr[d + 1];
    #pragma unroll 1
    for (; e + 8 <= e1; e += 8) {
        int2 m[8];
        #pragma unroll
        for (int j = 0; j < 8; ++j) m[j] = meta[e + j];
        float va[8], vb[8];
        #pragma unroll
        for (int j = 0; j < 8; ++j) {
            size_t o = (size_t)m[j].x * 64 + lane;
            va[j] = __half2float(xw1h[o]);
            vb[j] = __half2float(xw2h[o]);
        }
        #pragma unroll
        for (int j = 0; j < 8; ++j) {
            float nrm = __int_as_float(m[j].y);
            acc1 = fmaf(va[j], nrm, acc1);
            acc2 = fmaf(vb[j], nrm, acc2);
        }
    }
    if (e + 4 <= e1) {
        int2 m[4];
        #pragma unroll
        for (int j = 0; j < 4; ++j) m[j] = meta[e + j];
        float va[4], vb[4];
        #pragma unroll
        for (int j = 0; j < 4; ++j) {
            size_t o = (size_t)m[j].x * 64 + lane;
            va[j] = __half2float(xw1h[o]);
            vb[j] = __half2float(xw2h[o]);
        }
        #pragma unroll
        for (int j = 0; j < 4; ++j) {
            float nrm = __int_as_float(m[j].y);
            acc1 = fmaf(va[j], nrm, acc1);
            acc2 = fmaf(vb[j], nrm, acc2);
        }
        e += 4;
    }
    #pragma unroll 1
    for (; e < e1; ++e) {
        int2 m = meta[e];
        float nrm = __int_as_float(m.y);
        size_t o = (size_t)m.x * 64 + lane;
        acc1 = fmaf(__half2float(xw1h[o]), nrm, acc1);
        acc2 = fmaf(__half2float(xw2h[o]), nrm, acc2);
    }
    float r1 = elu_f(acc1 + b1[lane]);
    float xv = r1 + elu_f(acc2 + b2[lane]);
    // logits: per-lane row of Wl [64][16], butterfly reduce across 64 lanes
    const float4* wrow = (const float4*)(Wl + lane * 16);
    float4 w0 = wrow[0], w1 = wrow[1], w2 = wrow[2], w3 = wrow[3];
    float p[16];
    p[ 0]=xv*w0.x; p[ 1]=xv*w0.y; p[ 2]=xv*w0.z; p[ 3]=xv*w0.w;
    p[ 4]=xv*w1.x; p[ 5]=xv*w1.y; p[ 6]=xv*w1.z; p[ 7]=xv*w1.w;
    p[ 8]=xv*w2.x; p[ 9]=xv*w2.y; p[10]=xv*w2.z; p[11]=xv*w2.w;
    p[12]=xv*w3.x; p[13]=xv*w3.y; p[14]=xv*w3.z; p[15]=xv*w3.w;
    #pragma unroll
    for (int off = 32; off >= 1; off >>= 1) {
        #pragma unroll
        for (int c = 0; c < 16; ++c)
            p[c] += __shfl_xor(p[c], off, 64);
    }
    float4 bb0 = ((const float4*)bl)[0];
    float4 bb1 = ((const float4*)bl)[1];
    float4 bb2 = ((const float4*)bl)[2];
    float4 bb3 = ((const float4*)bl)[3];
    p[ 0]+=bb0.x; p[ 1]+=bb0.y; p[ 2]+=bb0.z; p[ 3]+=bb0.w;
    p[ 4]+=bb1.x; p[ 5]+=bb1.y; p[ 6]+=bb1.z; p[ 7]+=bb1.w;
    p[ 8]+=bb2.x; p[ 9]+=bb2.y; p[10]+=bb2.z; p[11]+=bb2.w;
    p[12]+=bb3.x; p[13]+=bb3.y; p[14]+=bb3.z; p[15]+=bb3.w;
    float m = p[0];
    #pragma unroll
    for (int c = 1; c < 16; ++c) m = fmaxf(m, p[c]);
    float es = 0.f;
    #pragma unroll
    for (int c = 0; c < 16; ++c) es += __expf(p[c] - m);
    float lse = m + __logf(es);
    if (lane == 0) {
        float4* po = (float4*)(outp + (size_t)d * 16);
        po[0] = make_float4(p[ 0]-lse, p[ 1]-lse, p[ 2]-lse, p[ 3]-lse);
        po[1] = make_float4(p[ 4]-lse, p[ 5]-lse, p[ 6]-lse, p[ 7]-lse);
        po[2] = make_float4(p[ 8]-lse, p[ 9]-lse, p[10]-lse, p[11]-lse);
        po[3] = make_float4(p[12]-lse, p[13]-lse, p[14]-lse, p[15]-lse);
    }
}

// ---------- launch ----------
extern "C" void kernel_launch(void* const* d_in, const int* in_sizes, int n_in,
                              void* d_out, int out_size, void* d_ws, size_t ws_size,
                              hipStream_t stream)
{
    const int*   node_index = (const int*)d_in[0];
    const int*   edge_index = (const int*)d_in[1];
    const float* ew  = (const float*)d_in[2];
    const float* emb = (const float*)d_in[3];
    const float* W1  = (const float*)d_in[4];
    const float* b1  = (const float*)d_in[5];
    const float* W2  = (const float*)d_in[6];
    const float* b2  = (const float*)d_in[7];
    const float* Wf  = (const float*)d_in[8];
    const float* bfv = (const float*)d_in[9];
    const float* Wl  = (const float*)d_in[10];
    const float* bl  = (const float*)d_in[11];

    const int N = in_sizes[0];
    const int E = in_sizes[2];
    const int* srcp = edge_index;
    const int* dstp = edge_index + E;

    char* ws = (char*)d_ws;
    size_t off = 0;
    auto alloc = [&](size_t bytes) {
        void* p = ws + off;
        off += (bytes + 255) & ~size_t(255);
        return p;
    };
    double* packed = (double*)alloc((size_t)N * 8);
    int*    rank   = (int*)   alloc((size_t)E * 4);
    int*    cnt    = (int*)   alloc((size_t)N * 4);
    int*    bsum   = (int*)   alloc(512 * 4);
    int*    rowptr = (int*)   alloc((size_t)(N + 1) * 4);
    float*  dinv   = (float*) alloc((size_t)N * 4);
    int2*   meta   = (int2*)  alloc((size_t)E * 8);
    __half* xw1h   = (__half*)alloc((size_t)N * 64 * 2);
    __half* xw2h   = (__half*)alloc((size_t)N * 64 * 2);

    int nb_nodes  = (N + 255) / 256;                        // 391 (<=512 for scan)
    int nb_edges  = (E + 255) / 256;
    int nb_gather = (N + 3) / 4;                            // 4 waves (nodes) per block

    hipMemsetAsync(packed, 0, (size_t)N * 8, stream);
    k_hist<<<nb_edges, 256, 0, stream>>>(dstp, ew, packed, rank, E);
    k_decode_blocksum<<<nb_nodes, 256, 0, stream>>>(packed, dinv, cnt, bsum, N);
    k_scan_bsum<<<1, 512, 0, stream>>>(bsum, nb_nodes);
    k_scan_apply<<<nb_nodes, 256, 0, stream>>>(cnt, bsum, rowptr, N);
    k_fill<<<nb_edges, 256, 0, stream>>>(srcp, dstp, ew, rank, dinv, rowptr, meta, E);
    k_front<<<nb_nodes, 256, 0, stream>>>(node_index, emb, W1, Wf, bfv, W2, xw1h, xw2h, N);
    k_gather<<<nb_gather, 256, 0, stream>>>(meta, rowptr, dinv, xw1h, xw2h,
                                            b1, b2, Wl, bl, (float*)d_out, N);
}

// Round 7
// 351.433 us; speedup vs baseline: 3.1537x; 1.2505x over previous
//
#include <hip/hip_runtime.h>
#include <hip/hip_fp16.h>
#include <math.h>

#define PACK     67108864.0              // 2^26
#define PACK_INV 1.4901161193847656e-08  // 2^-26

typedef _Float16 half8 __attribute__((ext_vector_type(8)));
typedef float    f32x4 __attribute__((ext_vector_type(4)));

// ---------- helpers ----------
__device__ __forceinline__ float elu_f(float v) {
    return v > 0.f ? v : expm1f(v);
}
// granule swizzle within a 64-fp16 row: spreads the 16B granules across banks
__device__ __forceinline__ int swz(int line, int e) {
    return ((((e >> 3) ^ (line & 7)) << 3) | (e & 7));
}

// ---------- K1: packed[dst] += ew + 2^26 ; rank[e] = previous count ----------
__global__ __launch_bounds__(256) void k_hist(const int* __restrict__ dst,
                                              const float* __restrict__ ew,
                                              double* __restrict__ packed,
                                              int* __restrict__ rank, int E) {
    int i = blockIdx.x * 256 + threadIdx.x;
    if (i < E) {
        double old = unsafeAtomicAdd(&packed[dst[i]], (double)ew[i] + PACK);
        rank[i] = (int)(old * PACK_INV);   // floor: frac part < 2^-20
    }
}

// ---------- K2: decode packed -> dinv + cnt ; per-block sums of cnt ----------
__global__ __launch_bounds__(256) void k_decode_blocksum(
    const double* __restrict__ packed,
    float* __restrict__ dinv,
    int* __restrict__ cnt,
    int* __restrict__ bsum, int n)
{
    __shared__ int sm[256];
    int t = threadIdx.x;
    int i = blockIdx.x * 256 + t;
    int v = 0;
    if (i < n) {
        double val = packed[i];
        double c = floor(val * PACK_INV);
        v = (int)c;
        float deg = (float)(val - c * PACK);
        dinv[i] = rsqrtf(deg + 1.0f);
        cnt[i] = v;
    }
    sm[t] = v;
    __syncthreads();
    for (int off = 128; off > 0; off >>= 1) {
        if (t < off) sm[t] += sm[t + off];
        __syncthreads();
    }
    if (t == 0) bsum[blockIdx.x] = sm[0];
}

// ---------- scan step 2: exclusive scan of block sums (single block, nb<=512) ----------
__global__ __launch_bounds__(512) void k_scan_bsum(int* __restrict__ bsum, int nb) {
    __shared__ int sm[512];
    int t = threadIdx.x;
    int v = (t < nb) ? bsum[t] : 0;
    sm[t] = v;
    __syncthreads();
    for (int off = 1; off < 512; off <<= 1) {
        int x = sm[t];
        int y = (t >= off) ? sm[t - off] : 0;
        __syncthreads();
        sm[t] = x + y;
        __syncthreads();
    }
    if (t < nb) bsum[t] = sm[t] - v;   // exclusive
}

// ---------- scan step 3: rowptr = blockoff + intra-block exclusive scan ----------
__global__ __launch_bounds__(256) void k_scan_apply(const int* __restrict__ cnt,
                                                    const int* __restrict__ bsum,
                                                    int* __restrict__ rowptr, int n) {
    __shared__ int sm[256];
    int t = threadIdx.x;
    int i = blockIdx.x * 256 + t;
    int v = (i < n) ? cnt[i] : 0;
    sm[t] = v;
    __syncthreads();
    for (int off = 1; off < 256; off <<= 1) {
        int x = sm[t];
        int y = (t >= off) ? sm[t - off] : 0;
        __syncthreads();
        sm[t] = x + y;
        __syncthreads();
    }
    int excl = sm[t] - v + bsum[blockIdx.x];
    if (i < n) {
        rowptr[i] = excl;
        if (i == n - 1) rowptr[n] = excl + v;
    }
}

// ---------- K-fill (atomic-free): meta[rowptr[dst]+rank] = (src, norm) ----------
__global__ __launch_bounds__(256) void k_fill(const int* __restrict__ src,
                                              const int* __restrict__ dst,
                                              const float* __restrict__ ew,
                                              const int* __restrict__ rank,
                                              const float* __restrict__ dinv,
                                              const int* __restrict__ rowptr,
                                              int2* __restrict__ meta, int E) {
    int i = blockIdx.x * 256 + threadIdx.x;
    if (i >= E) return;
    int s = src[i], d = dst[i];
    float nrm = dinv[s] * ew[i] * dinv[d];
    int pos = rowptr[d] + rank[i];
    meta[pos] = make_int2(s, __float_as_int(nrm));
}

// ---------- K-front (MFMA): xw1 = X@W1 ; xf = elu(X@Wf+bf) ; xw2 = xf@W2 ----------
// Block = 64 node rows, 4 waves; each wave owns 16 rows.
// LDS: X tile [64 rows][64 k] fp16 (granule-swizzled), 3x W^T [col][k] fp16.
// mfma_f32_16x16x32_f16: A row = lane&15, k = (lane>>4)*8+j (consistent A/B);
// C/D: col = lane&15, row = (lane>>4)*4 + reg  [HW-verified m89].
__global__ __launch_bounds__(256) void k_front(
    const int* __restrict__ node_index,
    const float* __restrict__ emb,
    const float* __restrict__ W1,
    const float* __restrict__ Wf,
    const float* __restrict__ bfv,
    const float* __restrict__ W2,
    __half* __restrict__ xw1h,
    __half* __restrict__ xw2h,
    int n)
{
    __shared__ _Float16 sX[64 * 64];       // 8 KB, later overwritten by xf (own rows only)
    __shared__ _Float16 sWt[3 * 64 * 64];  // 24 KB, W^T per matrix
    __shared__ float    sB[64];
    int t = threadIdx.x;
    int base = blockIdx.x * 64;

    // ---- stage X tile (fp16, swizzled) ----
    {
        int r = t >> 2, q = t & 3;
        int grow = base + r; if (grow >= n) grow = n - 1;
        int idx = node_index[grow];
        const float4* srcp = (const float4*)(emb + (size_t)idx * 64 + q * 16);
        float4 v0 = srcp[0], v1 = srcp[1], v2 = srcp[2], v3 = srcp[3];
        half8 h0, h1;
        h0[0]=(_Float16)v0.x; h0[1]=(_Float16)v0.y; h0[2]=(_Float16)v0.z; h0[3]=(_Float16)v0.w;
        h0[4]=(_Float16)v1.x; h0[5]=(_Float16)v1.y; h0[6]=(_Float16)v1.z; h0[7]=(_Float16)v1.w;
        h1[0]=(_Float16)v2.x; h1[1]=(_Float16)v2.y; h1[2]=(_Float16)v2.z; h1[3]=(_Float16)v2.w;
        h1[4]=(_Float16)v3.x; h1[5]=(_Float16)v3.y; h1[6]=(_Float16)v3.z; h1[7]=(_Float16)v3.w;
        int g0 = q * 2;
        *(half8*)&sX[r * 64 + (((g0    ) ^ (r & 7)) << 3)] = h0;
        *(half8*)&sX[r * 64 + (((g0 + 1) ^ (r & 7)) << 3)] = h1;
    }
    // ---- stage W1, Wf, W2 transposed (fp16, swizzled) ----
    {
        int kk = t >> 4;          // 0..15
        int c0 = (t & 15) * 4;    // 0..60
        #pragma unroll
        for (int m = 0; m < 3; ++m) {
            const float* W = (m == 0) ? W1 : (m == 1) ? Wf : W2;
            #pragma unroll
            for (int p = 0; p < 4; ++p) {
                int k = p * 16 + kk;
                float4 w = *(const float4*)(W + k * 64 + c0);
                sWt[m * 4096 + (c0 + 0) * 64 + swz(c0 + 0, k)] = (_Float16)w.x;
                sWt[m * 4096 + (c0 + 1) * 64 + swz(c0 + 1, k)] = (_Float16)w.y;
                sWt[m * 4096 + (c0 + 2) * 64 + swz(c0 + 2, k)] = (_Float16)w.z;
                sWt[m * 4096 + (c0 + 3) * 64 + swz(c0 + 3, k)] = (_Float16)w.w;
            }
        }
    }
    if (t < 64) sB[t] = bfv[t];
    __syncthreads();

    int w    = t >> 6;
    int lane = t & 63;
    int l15  = lane & 15;
    int kg   = lane >> 4;          // 0..3
    int row  = w * 16 + l15;       // A-operand row within block
    int rsw  = row & 7;

    // ---- GEMM1 + GEMMf (share A) ----
    half8 a0 = *(const half8*)&sX[row * 64 + (((kg    ) ^ rsw) << 3)];
    half8 a1 = *(const half8*)&sX[row * 64 + (((4 + kg) ^ rsw) << 3)];
    f32x4 acc1[4], accf[4];
    #pragma unroll
    for (int ct = 0; ct < 4; ++ct) {
        int col = ct * 16 + l15;
        int csw = col & 7;
        half8 b10 = *(const half8*)&sWt[         col * 64 + (((kg    ) ^ csw) << 3)];
        half8 b11 = *(const half8*)&sWt[         col * 64 + (((4 + kg) ^ csw) << 3)];
        half8 bf0 = *(const half8*)&sWt[4096   + col * 64 + (((kg    ) ^ csw) << 3)];
        half8 bf1 = *(const half8*)&sWt[4096   + col * 64 + (((4 + kg) ^ csw) << 3)];
        f32x4 z = {0.f, 0.f, 0.f, 0.f};
        f32x4 u = __builtin_amdgcn_mfma_f32_16x16x32_f16(a0, b10, z, 0, 0, 0);
        acc1[ct] = __builtin_amdgcn_mfma_f32_16x16x32_f16(a1, b11, u, 0, 0, 0);
        f32x4 v = __builtin_amdgcn_mfma_f32_16x16x32_f16(a0, bf0, z, 0, 0, 0);
        accf[ct] = __builtin_amdgcn_mfma_f32_16x16x32_f16(a1, bf1, v, 0, 0, 0);
    }
    // ---- write xw1 (global fp16 scatter) + xf (LDS, wave's own rows) ----
    #pragma unroll
    for (int ct = 0; ct < 4; ++ct) {
        int col = ct * 16 + l15;
        #pragma unroll
        for (int r = 0; r < 4; ++r) {
            int rloc = w * 16 + kg * 4 + r;
            int grow = base + rloc;
            if (grow < n) xw1h[(size_t)grow * 64 + col] = __float2half(acc1[ct][r]);
            float xfv = elu_f(accf[ct][r] + sB[col]);
            sX[rloc * 64 + swz(rloc, col)] = (_Float16)xfv;
        }
    }
    __syncthreads();
    // ---- GEMM2: xw2 = xf @ W2 ----
    half8 a20 = *(const half8*)&sX[row * 64 + (((kg    ) ^ rsw) << 3)];
    half8 a21 = *(const half8*)&sX[row * 64 + (((4 + kg) ^ rsw) << 3)];
    #pragma unroll
    for (int ct = 0; ct < 4; ++ct) {
        int col = ct * 16 + l15;
        int csw = col & 7;
        half8 b20 = *(const half8*)&sWt[8192 + col * 64 + (((kg    ) ^ csw) << 3)];
        half8 b21 = *(const half8*)&sWt[8192 + col * 64 + (((4 + kg) ^ csw) << 3)];
        f32x4 z = {0.f, 0.f, 0.f, 0.f};
        f32x4 u2 = __builtin_amdgcn_mfma_f32_16x16x32_f16(a20, b20, z, 0, 0, 0);
        f32x4 acc2 = __builtin_amdgcn_mfma_f32_16x16x32_f16(a21, b21, u2, 0, 0, 0);
        #pragma unroll
        for (int r = 0; r < 4; ++r) {
            int grow = base + w * 16 + kg * 4 + r;
            if (grow < n) xw2h[(size_t)grow * 64 + col] = __float2half(acc2[r]);
        }
    }
}

// ---------- K-gather (fused both convs + classifier + log_softmax) ----------
// one wave per dst node, lane = feature dim; unroll-8 => 16 row loads in flight
__global__ __launch_bounds__(256) void k_gather(
    const int2* __restrict__ meta,
    const int*  __restrict__ rowptr,
    const float* __restrict__ dinv,
    const __half* __restrict__ xw1h,
    const __half* __restrict__ xw2h,
    const float* __restrict__ b1,
    const float* __restrict__ b2,
    const float* __restrict__ Wl,
    const float* __restrict__ bl,
    float* __restrict__ outp,
    int n)
{
    int lane = threadIdx.x & 63;
    int d = __builtin_amdgcn_readfirstlane(blockIdx.x * 4 + (threadIdx.x >> 6));
    if (d >= n) return;
    float di = dinv[d];
    float di2 = di * di;
    float acc1 = __half2float(xw1h[(size_t)d * 64 + lane]) * di2;  // self-loop
    float acc2 = __half2float(xw2h[(size_t)d * 64 + lane]) * di2;
    int e = rowptr[d], e1 = rowptr[d + 1];
    #pragma unroll 1
    for (; e + 8 <= e1; e += 8) {
        int2 m[8];
        #pragma unroll
        for (int j = 0; j < 8; ++j) m[j] = meta[e + j];
        float va[8], vb[8];
        #pragma unroll
        for (int j = 0; j < 8; ++j) {
            size_t o = (size_t)m[j].x * 64 + lane;
            va[j] = __half2float(xw1h[o]);
            vb[j] = __half2float(xw2h[o]);
        }
        #pragma unroll
        for (int j = 0; j < 8; ++j) {
            float nrm = __int_as_float(m[j].y);
            acc1 = fmaf(va[j], nrm, acc1);
            acc2 = fmaf(vb[j], nrm, acc2);
        }
    }
    if (e + 4 <= e1) {
        int2 m[4];
        #pragma unroll
        for (int j = 0; j < 4; ++j) m[j] = meta[e + j];
        float va[4], vb[4];
        #pragma unroll
        for (int j = 0; j < 4; ++j) {
            size_t o = (size_t)m[j].x * 64 + lane;
            va[j] = __half2float(xw1h[o]);
            vb[j] = __half2float(xw2h[o]);
        }
        #pragma unroll
        for (int j = 0; j < 4; ++j) {
            float nrm = __int_as_float(m[j].y);
            acc1 = fmaf(va[j], nrm, acc1);
            acc2 = fmaf(vb[j], nrm, acc2);
        }
        e += 4;
    }
    #pragma unroll 1
    for (; e < e1; ++e) {
        int2 m = meta[e];
        float nrm = __int_as_float(m.y);
        size_t o = (size_t)m.x * 64 + lane;
        acc1 = fmaf(__half2float(xw1h[o]), nrm, acc1);
        acc2 = fmaf(__half2float(xw2h[o]), nrm, acc2);
    }
    float r1 = elu_f(acc1 + b1[lane]);
    float xv = r1 + elu_f(acc2 + b2[lane]);
    // logits: per-lane row of Wl [64][16], butterfly reduce across 64 lanes
    const float4* wrow = (const float4*)(Wl + lane * 16);
    float4 w0 = wrow[0], w1 = wrow[1], w2 = wrow[2], w3 = wrow[3];
    float p[16];
    p[ 0]=xv*w0.x; p[ 1]=xv*w0.y; p[ 2]=xv*w0.z; p[ 3]=xv*w0.w;
    p[ 4]=xv*w1.x; p[ 5]=xv*w1.y; p[ 6]=xv*w1.z; p[ 7]=xv*w1.w;
    p[ 8]=xv*w2.x; p[ 9]=xv*w2.y; p[10]=xv*w2.z; p[11]=xv*w2.w;
    p[12]=xv*w3.x; p[13]=xv*w3.y; p[14]=xv*w3.z; p[15]=xv*w3.w;
    #pragma unroll
    for (int off = 32; off >= 1; off >>= 1) {
        #pragma unroll
        for (int c = 0; c < 16; ++c)
            p[c] += __shfl_xor(p[c], off, 64);
    }
    float4 bb0 = ((const float4*)bl)[0];
    float4 bb1 = ((const float4*)bl)[1];
    float4 bb2 = ((const float4*)bl)[2];
    float4 bb3 = ((const float4*)bl)[3];
    p[ 0]+=bb0.x; p[ 1]+=bb0.y; p[ 2]+=bb0.z; p[ 3]+=bb0.w;
    p[ 4]+=bb1.x; p[ 5]+=bb1.y; p[ 6]+=bb1.z; p[ 7]+=bb1.w;
    p[ 8]+=bb2.x; p[ 9]+=bb2.y; p[10]+=bb2.z; p[11]+=bb2.w;
    p[12]+=bb3.x; p[13]+=bb3.y; p[14]+=bb3.z; p[15]+=bb3.w;
    float m = p[0];
    #pragma unroll
    for (int c = 1; c < 16; ++c) m = fmaxf(m, p[c]);
    float es = 0.f;
    #pragma unroll
    for (int c = 0; c < 16; ++c) es += __expf(p[c] - m);
    float lse = m + __logf(es);
    if (lane == 0) {
        float4* po = (float4*)(outp + (size_t)d * 16);
        po[0] = make_float4(p[ 0]-lse, p[ 1]-lse, p[ 2]-lse, p[ 3]-lse);
        po[1] = make_float4(p[ 4]-lse, p[ 5]-lse, p[ 6]-lse, p[ 7]-lse);
        po[2] = make_float4(p[ 8]-lse, p[ 9]-lse, p[10]-lse, p[11]-lse);
        po[3] = make_float4(p[12]-lse, p[13]-lse, p[14]-lse, p[15]-lse);
    }
}

// ---------- launch ----------
extern "C" void kernel_launch(void* const* d_in, const int* in_sizes, int n_in,
                              void* d_out, int out_size, void* d_ws, size_t ws_size,
                              hipStream_t stream)
{
    const int*   node_index = (const int*)d_in[0];
    const int*   edge_index = (const int*)d_in[1];
    const float* ew  = (const float*)d_in[2];
    const float* emb = (const float*)d_in[3];
    const float* W1  = (const float*)d_in[4];
    const float* b1  = (const float*)d_in[5];
    const float* W2  = (const float*)d_in[6];
    const float* b2  = (const float*)d_in[7];
    const float* Wf  = (const float*)d_in[8];
    const float* bfv = (const float*)d_in[9];
    const float* Wl  = (const float*)d_in[10];
    const float* bl  = (const float*)d_in[11];

    const int N = in_sizes[0];
    const int E = in_sizes[2];
    const int* srcp = edge_index;
    const int* dstp = edge_index + E;

    char* ws = (char*)d_ws;
    size_t off = 0;
    auto alloc = [&](size_t bytes) {
        void* p = ws + off;
        off += (bytes + 255) & ~size_t(255);
        return p;
    };
    double* packed = (double*)alloc((size_t)N * 8);
    int*    rank   = (int*)   alloc((size_t)E * 4);
    int*    cnt    = (int*)   alloc((size_t)N * 4);
    int*    bsum   = (int*)   alloc(512 * 4);
    int*    rowptr = (int*)   alloc((size_t)(N + 1) * 4);
    float*  dinv   = (float*) alloc((size_t)N * 4);
    int2*   meta   = (int2*)  alloc((size_t)E * 8);
    __half* xw1h   = (__half*)alloc((size_t)N * 64 * 2);
    __half* xw2h   = (__half*)alloc((size_t)N * 64 * 2);

    int nb_nodes  = (N + 255) / 256;                        // 391 (<=512 for scan)
    int nb_edges  = (E + 255) / 256;
    int nb_front  = (N + 63) / 64;                          // 64 rows per block
    int nb_gather = (N + 3) / 4;                            // 4 waves (nodes) per block

    hipMemsetAsync(packed, 0, (size_t)N * 8, stream);
    k_hist<<<nb_edges, 256, 0, stream>>>(dstp, ew, packed, rank, E);
    k_decode_blocksum<<<nb_nodes, 256, 0, stream>>>(packed, dinv, cnt, bsum, N);
    k_scan_bsum<<<1, 512, 0, stream>>>(bsum, nb_nodes);
    k_scan_apply<<<nb_nodes, 256, 0, stream>>>(cnt, bsum, rowptr, N);
    k_fill<<<nb_edges, 256, 0, stream>>>(srcp, dstp, ew, rank, dinv, rowptr, meta, E);
    k_front<<<nb_front, 256, 0, stream>>>(node_index, emb, W1, Wf, bfv, W2, xw1h, xw2h, N);
    k_gather<<<nb_gather, 256, 0, stream>>>(meta, rowptr, dinv, xw1h, xw2h,
                                            b1, b2, Wl, bl, (float*)d_out, N);
}

// Round 9
// 345.978 us; speedup vs baseline: 3.2035x; 1.0158x over previous
//
#include <hip/hip_runtime.h>
#include <hip/hip_fp16.h>
#include <math.h>

#define PACK     67108864.0              // 2^26
#define PACK_INV 1.4901161193847656e-08  // 2^-26

typedef _Float16 half8 __attribute__((ext_vector_type(8)));
typedef float    f32x4 __attribute__((ext_vector_type(4)));

// ---------- helpers ----------
__device__ __forceinline__ float elu_f(float v) {
    return v > 0.f ? v : expm1f(v);
}
__device__ __forceinline__ unsigned pack2h(float a, float b) {
    __half2 h = __floats2half2_rn(a, b);
    return *(unsigned*)&h;
}
__device__ __forceinline__ float2 unpack2h(unsigned u) {
    __half2 h = *(__half2*)&u;
    return __half22float2(h);
}
// granule swizzle within a 64-fp16 row: spreads the 16B granules across banks
__device__ __forceinline__ int swz(int line, int e) {
    return ((((e >> 3) ^ (line & 7)) << 3) | (e & 7));
}

// ---------- K1: packed[dst] += ew + 2^26 ; rank[e] = previous count ----------
__global__ __launch_bounds__(256) void k_hist(const int* __restrict__ dst,
                                              const float* __restrict__ ew,
                                              double* __restrict__ packed,
                                              int* __restrict__ rank, int E) {
    int i = blockIdx.x * 256 + threadIdx.x;
    if (i < E) {
        double old = unsafeAtomicAdd(&packed[dst[i]], (double)ew[i] + PACK);
        rank[i] = (int)(old * PACK_INV);   // floor: frac part < 2^-20
    }
}

// ---------- K2: decode packed -> dinv + cnt ; per-block sums of cnt ----------
__global__ __launch_bounds__(256) void k_decode_blocksum(
    const double* __restrict__ packed,
    float* __restrict__ dinv,
    int* __restrict__ cnt,
    int* __restrict__ bsum, int n)
{
    __shared__ int sm[256];
    int t = threadIdx.x;
    int i = blockIdx.x * 256 + t;
    int v = 0;
    if (i < n) {
        double val = packed[i];
        double c = floor(val * PACK_INV);
        v = (int)c;
        float deg = (float)(val - c * PACK);
        dinv[i] = rsqrtf(deg + 1.0f);
        cnt[i] = v;
    }
    sm[t] = v;
    __syncthreads();
    for (int off = 128; off > 0; off >>= 1) {
        if (t < off) sm[t] += sm[t + off];
        __syncthreads();
    }
    if (t == 0) bsum[blockIdx.x] = sm[0];
}

// ---------- scan step 2: exclusive scan of block sums (single block, nb<=512) ----------
__global__ __launch_bounds__(512) void k_scan_bsum(int* __restrict__ bsum, int nb) {
    __shared__ int sm[512];
    int t = threadIdx.x;
    int v = (t < nb) ? bsum[t] : 0;
    sm[t] = v;
    __syncthreads();
    for (int off = 1; off < 512; off <<= 1) {
        int x = sm[t];
        int y = (t >= off) ? sm[t - off] : 0;
        __syncthreads();
        sm[t] = x + y;
        __syncthreads();
    }
    if (t < nb) bsum[t] = sm[t] - v;   // exclusive
}

// ---------- scan step 3: rowptr = blockoff + intra-block exclusive scan ----------
__global__ __launch_bounds__(256) void k_scan_apply(const int* __restrict__ cnt,
                                                    const int* __restrict__ bsum,
                                                    int* __restrict__ rowptr, int n) {
    __shared__ int sm[256];
    int t = threadIdx.x;
    int i = blockIdx.x * 256 + t;
    int v = (i < n) ? cnt[i] : 0;
    sm[t] = v;
    __syncthreads();
    for (int off = 1; off < 256; off <<= 1) {
        int x = sm[t];
        int y = (t >= off) ? sm[t - off] : 0;
        __syncthreads();
        sm[t] = x + y;
        __syncthreads();
    }
    int excl = sm[t] - v + bsum[blockIdx.x];
    if (i < n) {
        rowptr[i] = excl;
        if (i == n - 1) rowptr[n] = excl + v;
    }
}

// ---------- K-fill (atomic-free): meta[rowptr[dst]+rank] = (src, norm) ----------
__global__ __launch_bounds__(256) void k_fill(const int* __restrict__ src,
                                              const int* __restrict__ dst,
                                              const float* __restrict__ ew,
                                              const int* __restrict__ rank,
                                              const float* __restrict__ dinv,
                                              const int* __restrict__ rowptr,
                                              int2* __restrict__ meta, int E) {
    int i = blockIdx.x * 256 + threadIdx.x;
    if (i >= E) return;
    int s = src[i], d = dst[i];
    float nrm = dinv[s] * ew[i] * dinv[d];
    int pos = rowptr[d] + rank[i];
    meta[pos] = make_int2(s, __float_as_int(nrm));
}

// ---------- K-front (MFMA): xw1 = X@W1 ; xf = elu(X@Wf+bf) ; xw2 = xf@W2 ----------
// Block = 64 node rows, 4 waves; each wave owns 16 rows.
// Output: xw12[node*64+col] = packed fp16 pair (xw1, xw2).
__global__ __launch_bounds__(256) void k_front(
    const int* __restrict__ node_index,
    const float* __restrict__ emb,
    const float* __restrict__ W1,
    const float* __restrict__ Wf,
    const float* __restrict__ bfv,
    const float* __restrict__ W2,
    unsigned* __restrict__ xw12,
    int n)
{
    __shared__ _Float16 sX[64 * 64];       // 8 KB, later overwritten by xf (own rows only)
    __shared__ _Float16 sWt[3 * 64 * 64];  // 24 KB, W^T per matrix
    __shared__ float    sB[64];
    int t = threadIdx.x;
    int base = blockIdx.x * 64;

    // ---- stage X tile (fp16, swizzled) ----
    {
        int r = t >> 2, q = t & 3;
        int grow = base + r; if (grow >= n) grow = n - 1;
        int idx = node_index[grow];
        const float4* srcp = (const float4*)(emb + (size_t)idx * 64 + q * 16);
        float4 v0 = srcp[0], v1 = srcp[1], v2 = srcp[2], v3 = srcp[3];
        half8 h0, h1;
        h0[0]=(_Float16)v0.x; h0[1]=(_Float16)v0.y; h0[2]=(_Float16)v0.z; h0[3]=(_Float16)v0.w;
        h0[4]=(_Float16)v1.x; h0[5]=(_Float16)v1.y; h0[6]=(_Float16)v1.z; h0[7]=(_Float16)v1.w;
        h1[0]=(_Float16)v2.x; h1[1]=(_Float16)v2.y; h1[2]=(_Float16)v2.z; h1[3]=(_Float16)v2.w;
        h1[4]=(_Float16)v3.x; h1[5]=(_Float16)v3.y; h1[6]=(_Float16)v3.z; h1[7]=(_Float16)v3.w;
        int g0 = q * 2;
        *(half8*)&sX[r * 64 + (((g0    ) ^ (r & 7)) << 3)] = h0;
        *(half8*)&sX[r * 64 + (((g0 + 1) ^ (r & 7)) << 3)] = h1;
    }
    // ---- stage W1, Wf, W2 transposed (fp16, swizzled) ----
    {
        int kk = t >> 4;          // 0..15
        int c0 = (t & 15) * 4;    // 0..60
        #pragma unroll
        for (int m = 0; m < 3; ++m) {
            const float* W = (m == 0) ? W1 : (m == 1) ? Wf : W2;
            #pragma unroll
            for (int p = 0; p < 4; ++p) {
                int k = p * 16 + kk;
                float4 w = *(const float4*)(W + k * 64 + c0);
                sWt[m * 4096 + (c0 + 0) * 64 + swz(c0 + 0, k)] = (_Float16)w.x;
                sWt[m * 4096 + (c0 + 1) * 64 + swz(c0 + 1, k)] = (_Float16)w.y;
                sWt[m * 4096 + (c0 + 2) * 64 + swz(c0 + 2, k)] = (_Float16)w.z;
                sWt[m * 4096 + (c0 + 3) * 64 + swz(c0 + 3, k)] = (_Float16)w.w;
            }
        }
    }
    if (t < 64) sB[t] = bfv[t];
    __syncthreads();

    int w    = t >> 6;
    int lane = t & 63;
    int l15  = lane & 15;
    int kg   = lane >> 4;          // 0..3
    int row  = w * 16 + l15;       // A-operand row within block
    int rsw  = row & 7;

    // ---- GEMM1 + GEMMf (share A) ----
    half8 a0 = *(const half8*)&sX[row * 64 + (((kg    ) ^ rsw) << 3)];
    half8 a1 = *(const half8*)&sX[row * 64 + (((4 + kg) ^ rsw) << 3)];
    f32x4 acc1[4], accf[4];
    #pragma unroll
    for (int ct = 0; ct < 4; ++ct) {
        int col = ct * 16 + l15;
        int csw = col & 7;
        half8 b10 = *(const half8*)&sWt[         col * 64 + (((kg    ) ^ csw) << 3)];
        half8 b11 = *(const half8*)&sWt[         col * 64 + (((4 + kg) ^ csw) << 3)];
        half8 bf0 = *(const half8*)&sWt[4096   + col * 64 + (((kg    ) ^ csw) << 3)];
        half8 bf1 = *(const half8*)&sWt[4096   + col * 64 + (((4 + kg) ^ csw) << 3)];
        f32x4 z = {0.f, 0.f, 0.f, 0.f};
        f32x4 u = __builtin_amdgcn_mfma_f32_16x16x32_f16(a0, b10, z, 0, 0, 0);
        acc1[ct] = __builtin_amdgcn_mfma_f32_16x16x32_f16(a1, b11, u, 0, 0, 0);
        f32x4 v = __builtin_amdgcn_mfma_f32_16x16x32_f16(a0, bf0, z, 0, 0, 0);
        accf[ct] = __builtin_amdgcn_mfma_f32_16x16x32_f16(a1, bf1, v, 0, 0, 0);
    }
    // ---- write xf (LDS, wave's own rows); keep acc1 in registers ----
    #pragma unroll
    for (int ct = 0; ct < 4; ++ct) {
        int col = ct * 16 + l15;
        #pragma unroll
        for (int r = 0; r < 4; ++r) {
            int rloc = w * 16 + kg * 4 + r;
            float xfv = elu_f(accf[ct][r] + sB[col]);
            sX[rloc * 64 + swz(rloc, col)] = (_Float16)xfv;
        }
    }
    __syncthreads();
    // ---- GEMM2: xw2 = xf @ W2 ; write packed (xw1, xw2) ----
    half8 a20 = *(const half8*)&sX[row * 64 + (((kg    ) ^ rsw) << 3)];
    half8 a21 = *(const half8*)&sX[row * 64 + (((4 + kg) ^ rsw) << 3)];
    #pragma unroll
    for (int ct = 0; ct < 4; ++ct) {
        int col = ct * 16 + l15;
        int csw = col & 7;
        half8 b20 = *(const half8*)&sWt[8192 + col * 64 + (((kg    ) ^ csw) << 3)];
        half8 b21 = *(const half8*)&sWt[8192 + col * 64 + (((4 + kg) ^ csw) << 3)];
        f32x4 z = {0.f, 0.f, 0.f, 0.f};
        f32x4 u2 = __builtin_amdgcn_mfma_f32_16x16x32_f16(a20, b20, z, 0, 0, 0);
        f32x4 acc2 = __builtin_amdgcn_mfma_f32_16x16x32_f16(a21, b21, u2, 0, 0, 0);
        #pragma unroll
        for (int r = 0; r < 4; ++r) {
            int grow = base + w * 16 + kg * 4 + r;
            if (grow < n)
                xw12[(size_t)grow * 64 + col] = pack2h(acc1[ct][r], acc2[r]);
        }
    }
}

// ---------- K-gather (fused both convs + classifier + log_softmax) ----------
// one wave per dst node, lane = feature dim; ONE packed uint load per edge
__global__ __launch_bounds__(256) void k_gather(
    const int2* __restrict__ meta,
    const int*  __restrict__ rowptr,
    const float* __restrict__ dinv,
    const unsigned* __restrict__ xw12,
    const float* __restrict__ b1,
    const float* __restrict__ b2,
    const float* __restrict__ Wl,
    const float* __restrict__ bl,
    float* __restrict__ outp,
    int n)
{
    int lane = threadIdx.x & 63;
    int d = __builtin_amdgcn_readfirstlane(blockIdx.x * 4 + (threadIdx.x >> 6));
    if (d >= n) return;
    float di = dinv[d];
    float di2 = di * di;
    float2 sf = unpack2h(xw12[(size_t)d * 64 + lane]);   // self-loop
    float acc1 = sf.x * di2;
    float acc2 = sf.y * di2;
    int e = rowptr[d], e1 = rowptr[d + 1];
    #pragma unroll 1
    for (; e + 8 <= e1; e += 8) {
        int2 m[8];
        #pragma unroll
        for (int j = 0; j < 8; ++j) m[j] = meta[e + j];
        unsigned u[8];
        #pragma unroll
        for (int j = 0; j < 8; ++j)
            u[j] = xw12[(size_t)m[j].x * 64 + lane];
        #pragma unroll
        for (int j = 0; j < 8; ++j) {
            float nrm = __int_as_float(m[j].y);
            float2 f = unpack2h(u[j]);
            acc1 = fmaf(f.x, nrm, acc1);
            acc2 = fmaf(f.y, nrm, acc2);
        }
    }
    if (e + 4 <= e1) {
        int2 m[4];
        #pragma unroll
        for (int j = 0; j < 4; ++j) m[j] = meta[e + j];
        unsigned u[4];
        #pragma unroll
        for (int j = 0; j < 4; ++j)
            u[j] = xw12[(size_t)m[j].x * 64 + lane];
        #pragma unroll
        for (int j = 0; j < 4; ++j) {
            float nrm = __int_as_float(m[j].y);
            float2 f = unpack2h(u[j]);
            acc1 = fmaf(f.x, nrm, acc1);
            acc2 = fmaf(f.y, nrm, acc2);
        }
        e += 4;
    }
    #pragma unroll 1
    for (; e < e1; ++e) {
        int2 m = meta[e];
        float nrm = __int_as_float(m.y);
        float2 f = unpack2h(xw12[(size_t)m.x * 64 + lane]);
        acc1 = fmaf(f.x, nrm, acc1);
        acc2 = fmaf(f.y, nrm, acc2);
    }
    float r1 = elu_f(acc1 + b1[lane]);
    float xv = r1 + elu_f(acc2 + b2[lane]);
    // logits: per-lane row of Wl [64][16], butterfly reduce across 64 lanes
    const float4* wrow = (const float4*)(Wl + lane * 16);
    float4 w0 = wrow[0], w1 = wrow[1], w2 = wrow[2], w3 = wrow[3];
    float p[16];
    p[ 0]=xv*w0.x; p[ 1]=xv*w0.y; p[ 2]=xv*w0.z; p[ 3]=xv*w0.w;
    p[ 4]=xv*w1.x; p[ 5]=xv*w1.y; p[ 6]=xv*w1.z; p[ 7]=xv*w1.w;
    p[ 8]=xv*w2.x; p[ 9]=xv*w2.y; p[10]=xv*w2.z; p[11]=xv*w2.w;
    p[12]=xv*w3.x; p[13]=xv*w3.y; p[14]=xv*w3.z; p[15]=xv*w3.w;
    #pragma unroll
    for (int off = 32; off >= 1; off >>= 1) {
        #pragma unroll
        for (int c = 0; c < 16; ++c)
            p[c] += __shfl_xor(p[c], off, 64);
    }
    float4 bb0 = ((const float4*)bl)[0];
    float4 bb1 = ((const float4*)bl)[1];
    float4 bb2 = ((const float4*)bl)[2];
    float4 bb3 = ((const float4*)bl)[3];
    p[ 0]+=bb0.x; p[ 1]+=bb0.y; p[ 2]+=bb0.z; p[ 3]+=bb0.w;
    p[ 4]+=bb1.x; p[ 5]+=bb1.y; p[ 6]+=bb1.z; p[ 7]+=bb1.w;
    p[ 8]+=bb2.x; p[ 9]+=bb2.y; p[10]+=bb2.z; p[11]+=bb2.w;
    p[12]+=bb3.x; p[13]+=bb3.y; p[14]+=bb3.z; p[15]+=bb3.w;
    float m = p[0];
    #pragma unroll
    for (int c = 1; c < 16; ++c) m = fmaxf(m, p[c]);
    float es = 0.f;
    #pragma unroll
    for (int c = 0; c < 16; ++c) es += __expf(p[c] - m);
    float lse = m + __logf(es);
    if (lane == 0) {
        float4* po = (float4*)(outp + (size_t)d * 16);
        po[0] = make_float4(p[ 0]-lse, p[ 1]-lse, p[ 2]-lse, p[ 3]-lse);
        po[1] = make_float4(p[ 4]-lse, p[ 5]-lse, p[ 6]-lse, p[ 7]-lse);
        po[2] = make_float4(p[ 8]-lse, p[ 9]-lse, p[10]-lse, p[11]-lse);
        po[3] = make_float4(p[12]-lse, p[13]-lse, p[14]-lse, p[15]-lse);
    }
}

// ---------- launch ----------
extern "C" void kernel_launch(void* const* d_in, const int* in_sizes, int n_in,
                              void* d_out, int out_size, void* d_ws, size_t ws_size,
                              hipStream_t stream)
{
    const int*   node_index = (const int*)d_in[0];
    const int*   edge_index = (const int*)d_in[1];
    const float* ew  = (const float*)d_in[2];
    const float* emb = (const float*)d_in[3];
    const float* W1  = (const float*)d_in[4];
    const float* b1  = (const float*)d_in[5];
    const float* W2  = (const float*)d_in[6];
    const float* b2  = (const float*)d_in[7];
    const float* Wf  = (const float*)d_in[8];
    const float* bfv = (const float*)d_in[9];
    const float* Wl  = (const float*)d_in[10];
    const float* bl  = (const float*)d_in[11];

    const int N = in_sizes[0];
    const int E = in_sizes[2];
    const int* srcp = edge_index;
    const int* dstp = edge_index + E;

    char* ws = (char*)d_ws;
    size_t off = 0;
    auto alloc = [&](size_t bytes) {
        void* p = ws + off;
        off += (bytes + 255) & ~size_t(255);
        return p;
    };
    double*   packed = (double*)  alloc((size_t)N * 8);
    int*      rank   = (int*)     alloc((size_t)E * 4);
    int*      cnt    = (int*)     alloc((size_t)N * 4);
    int*      bsum   = (int*)     alloc(512 * 4);
    int*      rowptr = (int*)     alloc((size_t)(N + 1) * 4);
    float*    dinv   = (float*)   alloc((size_t)N * 4);
    int2*     meta   = (int2*)    alloc((size_t)E * 8);
    unsigned* xw12   = (unsigned*)alloc((size_t)N * 64 * 4);

    int nb_nodes  = (N + 255) / 256;                        // 391 (<=512 for scan)
    int nb_edges  = (E + 255) / 256;
    int nb_front  = (N + 63) / 64;                          // 64 rows per block
    int nb_gather = (N + 3) / 4;                            // 4 waves (nodes) per block

    hipMemsetAsync(packed, 0, (size_t)N * 8, stream);
    k_hist<<<nb_edges, 256, 0, stream>>>(dstp, ew, packed, rank, E);
    k_decode_blocksum<<<nb_nodes, 256, 0, stream>>>(packed, dinv, cnt, bsum, N);
    k_scan_bsum<<<1, 512, 0, stream>>>(bsum, nb_nodes);
    k_scan_apply<<<nb_nodes, 256, 0, stream>>>(cnt, bsum, rowptr, N);
    k_fill<<<nb_edges, 256, 0, stream>>>(srcp, dstp, ew, rank, dinv, rowptr, meta, E);
    k_front<<<nb_front, 256, 0, stream>>>(node_index, emb, W1, Wf, bfv, W2, xw12, N);
    k_gather<<<nb_gather, 256, 0, stream>>>(meta, rowptr, dinv, xw12,
                                            b1, b2, Wl, bl, (float*)d_out, N);
}

// Round 12
// 328.809 us; speedup vs baseline: 3.3707x; 1.0522x over previous
//
#include <hip/hip_runtime.h>
#include <hip/hip_fp16.h>
#include <math.h>

#define PACK     67108864.0              // 2^26
#define PACK_INV 1.4901161193847656e-08  // 2^-26

typedef _Float16 half8 __attribute__((ext_vector_type(8)));
typedef float    f32x4 __attribute__((ext_vector_type(4)));

// ---------- helpers ----------
__device__ __forceinline__ float elu_f(float v) {
    return v > 0.f ? v : expm1f(v);
}
__device__ __forceinline__ unsigned pack2h(float a, float b) {
    __half2 h = __floats2half2_rn(a, b);
    return *(unsigned*)&h;
}
__device__ __forceinline__ float2 unpack2h(unsigned u) {
    __half2 h = *(__half2*)&u;
    return __half22float2(h);
}
// granule swizzle within a 64-fp16 row: spreads the 16B granules across banks
__device__ __forceinline__ int swz(int line, int e) {
    return ((((e >> 3) ^ (line & 7)) << 3) | (e & 7));
}

// ---------- K1: packed[dst] += ew + 2^26 ; rank[e] = previous count ----------
__global__ __launch_bounds__(256) void k_hist(const int* __restrict__ dst,
                                              const float* __restrict__ ew,
                                              double* __restrict__ packed,
                                              int* __restrict__ rank, int E) {
    int i = blockIdx.x * 256 + threadIdx.x;
    if (i < E) {
        double old = unsafeAtomicAdd(&packed[dst[i]], (double)ew[i] + PACK);
        rank[i] = (int)(old * PACK_INV);   // floor: frac part < 2^-20
    }
}

// ---------- K2: decode packed -> dinv + cnt ; per-block sums of cnt ----------
__global__ __launch_bounds__(256) void k_decode_blocksum(
    const double* __restrict__ packed,
    float* __restrict__ dinv,
    int* __restrict__ cnt,
    int* __restrict__ bsum, int n)
{
    __shared__ int sm[256];
    int t = threadIdx.x;
    int i = blockIdx.x * 256 + t;
    int v = 0;
    if (i < n) {
        double val = packed[i];
        double c = floor(val * PACK_INV);
        v = (int)c;
        float deg = (float)(val - c * PACK);
        dinv[i] = rsqrtf(deg + 1.0f);
        cnt[i] = v;
    }
    sm[t] = v;
    __syncthreads();
    for (int off = 128; off > 0; off >>= 1) {
        if (t < off) sm[t] += sm[t + off];
        __syncthreads();
    }
    if (t == 0) bsum[blockIdx.x] = sm[0];
}

// ---------- scan step 2: exclusive scan of block sums (single block, nb<=512) ----------
__global__ __launch_bounds__(512) void k_scan_bsum(int* __restrict__ bsum, int nb) {
    __shared__ int sm[512];
    int t = threadIdx.x;
    int v = (t < nb) ? bsum[t] : 0;
    sm[t] = v;
    __syncthreads();
    for (int off = 1; off < 512; off <<= 1) {
        int x = sm[t];
        int y = (t >= off) ? sm[t - off] : 0;
        __syncthreads();
        sm[t] = x + y;
        __syncthreads();
    }
    if (t < nb) bsum[t] = sm[t] - v;   // exclusive
}

// ---------- scan step 3: rowptr = blockoff + intra-block exclusive scan ----------
__global__ __launch_bounds__(256) void k_scan_apply(const int* __restrict__ cnt,
                                                    const int* __restrict__ bsum,
                                                    int* __restrict__ rowptr, int n) {
    __shared__ int sm[256];
    int t = threadIdx.x;
    int i = blockIdx.x * 256 + t;
    int v = (i < n) ? cnt[i] : 0;
    sm[t] = v;
    __syncthreads();
    for (int off = 1; off < 256; off <<= 1) {
        int x = sm[t];
        int y = (t >= off) ? sm[t - off] : 0;
        __syncthreads();
        sm[t] = x + y;
        __syncthreads();
    }
    int excl = sm[t] - v + bsum[blockIdx.x];
    if (i < n) {
        rowptr[i] = excl;
        if (i == n - 1) rowptr[n] = excl + v;
    }
}

// ---------- K-fill (atomic-free): meta[rowptr[dst]+rank] = (src, norm) ----------
__global__ __launch_bounds__(256) void k_fill(const int* __restrict__ src,
                                              const int* __restrict__ dst,
                                              const float* __restrict__ ew,
                                              const int* __restrict__ rank,
                                              const float* __restrict__ dinv,
                                              const int* __restrict__ rowptr,
                                              int2* __restrict__ meta, int E) {
    int i = blockIdx.x * 256 + threadIdx.x;
    if (i >= E) return;
    int s = src[i], d = dst[i];
    float nrm = dinv[s] * ew[i] * dinv[d];
    int pos = rowptr[d] + rank[i];
    meta[pos] = make_int2(s, __float_as_int(nrm));
}

// ---------- K-front (MFMA): xw1 = X@W1 ; xf = elu(X@Wf+bf) ; xw2 = xf@W2 ----------
// Block = 64 node rows, 4 waves; each wave owns 16 rows.
// Output: xw12[node*64+col] = packed fp16 pair (xw1, xw2).
__global__ __launch_bounds__(256) void k_front(
    const int* __restrict__ node_index,
    const float* __restrict__ emb,
    const float* __restrict__ W1,
    const float* __restrict__ Wf,
    const float* __restrict__ bfv,
    const float* __restrict__ W2,
    unsigned* __restrict__ xw12,
    int n)
{
    __shared__ _Float16 sX[64 * 64];       // 8 KB, later overwritten by xf (own rows only)
    __shared__ _Float16 sWt[3 * 64 * 64];  // 24 KB, W^T per matrix
    __shared__ float    sB[64];
    int t = threadIdx.x;
    int base = blockIdx.x * 64;

    // ---- stage X tile (fp16, swizzled) ----
    {
        int r = t >> 2, q = t & 3;
        int grow = base + r; if (grow >= n) grow = n - 1;
        int idx = node_index[grow];
        const float4* srcp = (const float4*)(emb + (size_t)idx * 64 + q * 16);
        float4 v0 = srcp[0], v1 = srcp[1], v2 = srcp[2], v3 = srcp[3];
        half8 h0, h1;
        h0[0]=(_Float16)v0.x; h0[1]=(_Float16)v0.y; h0[2]=(_Float16)v0.z; h0[3]=(_Float16)v0.w;
        h0[4]=(_Float16)v1.x; h0[5]=(_Float16)v1.y; h0[6]=(_Float16)v1.z; h0[7]=(_Float16)v1.w;
        h1[0]=(_Float16)v2.x; h1[1]=(_Float16)v2.y; h1[2]=(_Float16)v2.z; h1[3]=(_Float16)v2.w;
        h1[4]=(_Float16)v3.x; h1[5]=(_Float16)v3.y; h1[6]=(_Float16)v3.z; h1[7]=(_Float16)v3.w;
        int g0 = q * 2;
        *(half8*)&sX[r * 64 + (((g0    ) ^ (r & 7)) << 3)] = h0;
        *(half8*)&sX[r * 64 + (((g0 + 1) ^ (r & 7)) << 3)] = h1;
    }
    // ---- stage W1, Wf, W2 transposed (fp16, swizzled) ----
    {
        int kk = t >> 4;          // 0..15
        int c0 = (t & 15) * 4;    // 0..60
        #pragma unroll
        for (int m = 0; m < 3; ++m) {
            const float* W = (m == 0) ? W1 : (m == 1) ? Wf : W2;
            #pragma unroll
            for (int p = 0; p < 4; ++p) {
                int k = p * 16 + kk;
                float4 w = *(const float4*)(W + k * 64 + c0);
                sWt[m * 4096 + (c0 + 0) * 64 + swz(c0 + 0, k)] = (_Float16)w.x;
                sWt[m * 4096 + (c0 + 1) * 64 + swz(c0 + 1, k)] = (_Float16)w.y;
                sWt[m * 4096 + (c0 + 2) * 64 + swz(c0 + 2, k)] = (_Float16)w.z;
                sWt[m * 4096 + (c0 + 3) * 64 + swz(c0 + 3, k)] = (_Float16)w.w;
            }
        }
    }
    if (t < 64) sB[t] = bfv[t];
    __syncthreads();

    int w    = t >> 6;
    int lane = t & 63;
    int l15  = lane & 15;
    int kg   = lane >> 4;          // 0..3
    int row  = w * 16 + l15;       // A-operand row within block
    int rsw  = row & 7;

    // ---- GEMM1 + GEMMf (share A) ----
    half8 a0 = *(const half8*)&sX[row * 64 + (((kg    ) ^ rsw) << 3)];
    half8 a1 = *(const half8*)&sX[row * 64 + (((4 + kg) ^ rsw) << 3)];
    f32x4 acc1[4], accf[4];
    #pragma unroll
    for (int ct = 0; ct < 4; ++ct) {
        int col = ct * 16 + l15;
        int csw = col & 7;
        half8 b10 = *(const half8*)&sWt[         col * 64 + (((kg    ) ^ csw) << 3)];
        half8 b11 = *(const half8*)&sWt[         col * 64 + (((4 + kg) ^ csw) << 3)];
        half8 bf0 = *(const half8*)&sWt[4096   + col * 64 + (((kg    ) ^ csw) << 3)];
        half8 bf1 = *(const half8*)&sWt[4096   + col * 64 + (((4 + kg) ^ csw) << 3)];
        f32x4 z = {0.f, 0.f, 0.f, 0.f};
        f32x4 u = __builtin_amdgcn_mfma_f32_16x16x32_f16(a0, b10, z, 0, 0, 0);
        acc1[ct] = __builtin_amdgcn_mfma_f32_16x16x32_f16(a1, b11, u, 0, 0, 0);
        f32x4 v = __builtin_amdgcn_mfma_f32_16x16x32_f16(a0, bf0, z, 0, 0, 0);
        accf[ct] = __builtin_amdgcn_mfma_f32_16x16x32_f16(a1, bf1, v, 0, 0, 0);
    }
    // ---- write xf (LDS, wave's own rows); keep acc1 in registers ----
    #pragma unroll
    for (int ct = 0; ct < 4; ++ct) {
        int col = ct * 16 + l15;
        #pragma unroll
        for (int r = 0; r < 4; ++r) {
            int rloc = w * 16 + kg * 4 + r;
            float xfv = elu_f(accf[ct][r] + sB[col]);
            sX[rloc * 64 + swz(rloc, col)] = (_Float16)xfv;
        }
    }
    __syncthreads();
    // ---- GEMM2: xw2 = xf @ W2 ; write packed (xw1, xw2) ----
    half8 a20 = *(const half8*)&sX[row * 64 + (((kg    ) ^ rsw) << 3)];
    half8 a21 = *(const half8*)&sX[row * 64 + (((4 + kg) ^ rsw) << 3)];
    #pragma unroll
    for (int ct = 0; ct < 4; ++ct) {
        int col = ct * 16 + l15;
        int csw = col & 7;
        half8 b20 = *(const half8*)&sWt[8192 + col * 64 + (((kg    ) ^ csw) << 3)];
        half8 b21 = *(const half8*)&sWt[8192 + col * 64 + (((4 + kg) ^ csw) << 3)];
        f32x4 z = {0.f, 0.f, 0.f, 0.f};
        f32x4 u2 = __builtin_amdgcn_mfma_f32_16x16x32_f16(a20, b20, z, 0, 0, 0);
        f32x4 acc2 = __builtin_amdgcn_mfma_f32_16x16x32_f16(a21, b21, u2, 0, 0, 0);
        #pragma unroll
        for (int r = 0; r < 4; ++r) {
            int grow = base + w * 16 + kg * 4 + r;
            if (grow < n)
                xw12[(size_t)grow * 64 + col] = pack2h(acc1[ct][r], acc2[r]);
        }
    }
}

// ---------- K-gather (fused both convs + classifier + log_softmax) ----------
// one wave per dst node, lane = feature dim; ONE packed uint load per edge.
// Classifier: LDS-staged Wl^T + per-lane single-class partial dot (cheap epilogue).
__global__ __launch_bounds__(256) void k_gather(
    const int2* __restrict__ meta,
    const int*  __restrict__ rowptr,
    const float* __restrict__ dinv,
    const unsigned* __restrict__ xw12,
    const float* __restrict__ b1,
    const float* __restrict__ b2,
    const float* __restrict__ Wl,
    const float* __restrict__ bl,
    float* __restrict__ outp,
    int n)
{
    __shared__ float sWlT[16 * 68];   // Wl^T, padded row stride 68 floats
    __shared__ float sxv[4 * 64];     // per-wave xv staging
    int t = threadIdx.x;
    // stage Wl^T once per block: sWlT[c][k] = Wl[k][c]
    for (int i = t; i < 1024; i += 256) {
        int k = i & 63, c = i >> 6;            // c in 0..15 over 4 iterations
        sWlT[c * 68 + k] = Wl[k * 16 + c];
    }
    __syncthreads();

    int lane = t & 63;
    int wid  = t >> 6;
    int d = __builtin_amdgcn_readfirstlane(blockIdx.x * 4 + wid);
    if (d >= n) return;
    float di = dinv[d];
    float di2 = di * di;
    float2 sf = unpack2h(xw12[(size_t)d * 64 + lane]);   // self-loop
    float acc1 = sf.x * di2;
    float acc2 = sf.y * di2;
    int e = rowptr[d], e1 = rowptr[d + 1];
    #pragma unroll 1
    for (; e + 8 <= e1; e += 8) {
        int2 m[8];
        #pragma unroll
        for (int j = 0; j < 8; ++j) m[j] = meta[e + j];
        unsigned u[8];
        #pragma unroll
        for (int j = 0; j < 8; ++j)
            u[j] = xw12[(size_t)m[j].x * 64 + lane];
        #pragma unroll
        for (int j = 0; j < 8; ++j) {
            float nrm = __int_as_float(m[j].y);
            float2 f = unpack2h(u[j]);
            acc1 = fmaf(f.x, nrm, acc1);
            acc2 = fmaf(f.y, nrm, acc2);
        }
    }
    if (e + 4 <= e1) {
        int2 m[4];
        #pragma unroll
        for (int j = 0; j < 4; ++j) m[j] = meta[e + j];
        unsigned u[4];
        #pragma unroll
        for (int j = 0; j < 4; ++j)
            u[j] = xw12[(size_t)m[j].x * 64 + lane];
        #pragma unroll
        for (int j = 0; j < 4; ++j) {
            float nrm = __int_as_float(m[j].y);
            float2 f = unpack2h(u[j]);
            acc1 = fmaf(f.x, nrm, acc1);
            acc2 = fmaf(f.y, nrm, acc2);
        }
        e += 4;
    }
    #pragma unroll 1
    for (; e < e1; ++e) {
        int2 m = meta[e];
        float nrm = __int_as_float(m.y);
        float2 f = unpack2h(xw12[(size_t)m.x * 64 + lane]);
        acc1 = fmaf(f.x, nrm, acc1);
        acc2 = fmaf(f.y, nrm, acc2);
    }
    float r1 = elu_f(acc1 + b1[lane]);
    float xv = r1 + elu_f(acc2 + b2[lane]);

    // ---- classifier: lane (g = lane>>4, c = lane&15) computes one class
    //      partial over its 16-element slice; 2 shfl to merge groups ----
    sxv[wid * 64 + lane] = xv;                 // same-wave LDS rw, no barrier
    int g = lane >> 4, c = lane & 15;
    const float* xvp = &sxv[wid * 64 + g * 16];
    const float* wp  = &sWlT[c * 68 + g * 16];
    float partial = 0.f;
    #pragma unroll
    for (int p4 = 0; p4 < 4; ++p4) {
        float4 x4 = *(const float4*)(xvp + p4 * 4);   // broadcast within group
        float4 w4 = *(const float4*)(wp  + p4 * 4);
        partial = fmaf(x4.x, w4.x, partial);
        partial = fmaf(x4.y, w4.y, partial);
        partial = fmaf(x4.z, w4.z, partial);
        partial = fmaf(x4.w, w4.w, partial);
    }
    partial += __shfl_xor(partial, 16, 64);
    partial += __shfl_xor(partial, 32, 64);
    float logit = partial + bl[c];
    // softmax over the 16 classes spread across each 16-lane group
    float m = logit;
    #pragma unroll
    for (int off = 1; off < 16; off <<= 1)
        m = fmaxf(m, __shfl_xor(m, off, 64));
    float ex = __expf(logit - m);
    float es = ex;
    #pragma unroll
    for (int off = 1; off < 16; off <<= 1)
        es += __shfl_xor(es, off, 64);
    float lse = m + __logf(es);
    if (lane < 16)
        outp[(size_t)d * 16 + lane] = logit - lse;   // coalesced 64B row
}

// ---------- launch ----------
extern "C" void kernel_launch(void* const* d_in, const int* in_sizes, int n_in,
                              void* d_out, int out_size, void* d_ws, size_t ws_size,
                              hipStream_t stream)
{
    const int*   node_index = (const int*)d_in[0];
    const int*   edge_index = (const int*)d_in[1];
    const float* ew  = (const float*)d_in[2];
    const float* emb = (const float*)d_in[3];
    const float* W1  = (const float*)d_in[4];
    const float* b1  = (const float*)d_in[5];
    const float* W2  = (const float*)d_in[6];
    const float* b2  = (const float*)d_in[7];
    const float* Wf  = (const float*)d_in[8];
    const float* bfv = (const float*)d_in[9];
    const float* Wl  = (const float*)d_in[10];
    const float* bl  = (const float*)d_in[11];

    const int N = in_sizes[0];
    const int E = in_sizes[2];
    const int* srcp = edge_index;
    const int* dstp = edge_index + E;

    char* ws = (char*)d_ws;
    size_t off = 0;
    auto alloc = [&](size_t bytes) {
        void* p = ws + off;
        off += (bytes + 255) & ~size_t(255);
        return p;
    };
    double*   packed = (double*)  alloc((size_t)N * 8);
    int*      rank   = (int*)     alloc((size_t)E * 4);
    int*      cnt    = (int*)     alloc((size_t)N * 4);
    int*      bsum   = (int*)     alloc(512 * 4);
    int*      rowptr = (int*)     alloc((size_t)(N + 1) * 4);
    float*    dinv   = (float*)   alloc((size_t)N * 4);
    int2*     meta   = (int2*)    alloc((size_t)E * 8);
    unsigned* xw12   = (unsigned*)alloc((size_t)N * 64 * 4);

    int nb_nodes  = (N + 255) / 256;                        // 391 (<=512 for scan)
    int nb_edges  = (E + 255) / 256;
    int nb_front  = (N + 63) / 64;                          // 64 rows per block
    int nb_gather = (N + 3) / 4;                            // 4 waves (nodes) per block

    hipMemsetAsync(packed, 0, (size_t)N * 8, stream);
    k_hist<<<nb_edges, 256, 0, stream>>>(dstp, ew, packed, rank, E);
    k_decode_blocksum<<<nb_nodes, 256, 0, stream>>>(packed, dinv, cnt, bsum, N);
    k_scan_bsum<<<1, 512, 0, stream>>>(bsum, nb_nodes);
    k_scan_apply<<<nb_nodes, 256, 0, stream>>>(cnt, bsum, rowptr, N);
    k_fill<<<nb_edges, 256, 0, stream>>>(srcp, dstp, ew, rank, dinv, rowptr, meta, E);
    k_front<<<nb_front, 256, 0, stream>>>(node_index, emb, W1, Wf, bfv, W2, xw12, N);
    k_gather<<<nb_gather, 256, 0, stream>>>(meta, rowptr, dinv, xw12,
                                            b1, b2, Wl, bl, (float*)d_out, N);
}